// Round 1
// baseline (5286.168 us; speedup 1.0000x reference)
//
#include <hip/hip_runtime.h>
#include <math.h>

// Problem constants: T=4, B=4, C=2, H=W=128 (HW=16384), E=256, half=128.
#define HW 16384

// ---------------------------------------------------------------------------
// k_reorder: transpose w1 [256oc][128ic][9] -> wt1 [ic*9+tap][256oc]
//            and w_res [256oc][128ic] -> wrt [ic][256oc]
// so the big kernel can stage weights with coalesced float4 loads.
// ---------------------------------------------------------------------------
__global__ __launch_bounds__(256)
void k_reorder(const float* __restrict__ w1, const float* __restrict__ wres,
               float* __restrict__ wt1, float* __restrict__ wrt) {
    int i = blockIdx.x * 256 + threadIdx.x;
    if (i < 294912) {            // 1152 * 256
        int oc = i & 255, r = i >> 8;          // r = ic*9 + tap
        wt1[i] = w1[oc * 1152 + r];
    }
    if (i < 32768) {             // 128 * 256
        int oc = i & 255, ic = i >> 8;
        wrt[i] = wres[oc * 128 + ic];
    }
}

// ---------------------------------------------------------------------------
// k_proj (per t): x_in = x[t] + x_out;  3x3 conv 2->128 + BN + LIF(vp)
// writes s1[t] as uint8 spikes, updates vp.
// grid (4 Wtiles, 16 Htiles, B*4 oc-quarters), block 256 = 8 rows x 32 cols
// ---------------------------------------------------------------------------
__global__ __launch_bounds__(256)
void k_proj(const float* __restrict__ xt, const float* __restrict__ xout,
            const float* __restrict__ wp,
            const float* __restrict__ g, const float* __restrict__ bb,
            const float* __restrict__ mm, const float* __restrict__ vv,
            float* __restrict__ vp, unsigned char* __restrict__ s1t) {
    __shared__ float xin[2 * 10 * 36];
    const int tid = threadIdx.x;
    const int b   = blockIdx.z >> 2;
    const int ocq = blockIdx.z & 3;
    const int gy0 = blockIdx.y * 8, gx0 = blockIdx.x * 32;

    for (int i = tid; i < 680; i += 256) {          // 2ch * 10 * 34
        int ch = i / 340, rem = i % 340;
        int r = rem / 34, c = rem % 34;
        int gy = gy0 - 1 + r, gx = gx0 - 1 + c;
        float val = 0.f;
        if (gy >= 0 && gy < 128 && gx >= 0 && gx < 128) {
            int idx = ((b * 2 + ch) << 14) + (gy << 7) + gx;
            val = xt[idx] + xout[idx];
        }
        xin[(ch * 10 + r) * 36 + c] = val;
    }
    __syncthreads();

    const int prow = tid >> 5, pcol = tid & 31;
    float xw[2][3][3];
#pragma unroll
    for (int ch = 0; ch < 2; ++ch)
#pragma unroll
        for (int ky = 0; ky < 3; ++ky)
#pragma unroll
            for (int kx = 0; kx < 3; ++kx)
                xw[ch][ky][kx] = xin[(ch * 10 + prow + ky) * 36 + pcol + kx];

    const int pix = ((gy0 + prow) << 7) + gx0 + pcol;
    const int oc_beg = ocq * 32;
    for (int oc = oc_beg; oc < oc_beg + 32; ++oc) {
        float acc = 0.f;
#pragma unroll
        for (int ch = 0; ch < 2; ++ch)
#pragma unroll
            for (int ky = 0; ky < 3; ++ky)
#pragma unroll
                for (int kx = 0; kx < 3; ++kx)
                    acc = fmaf(wp[((oc * 2 + ch) * 3 + ky) * 3 + kx], xw[ch][ky][kx], acc);
        float sc = g[oc] / sqrtf(vv[oc] + 1e-5f);
        float h  = (acc - mm[oc]) * sc + bb[oc];
        int idx = ((b * 128 + oc) << 14) + pix;
        float v = vp[idx];
        v = v + (h - v) * 0.5f;
        bool s = (v >= 1.0f);
        vp[idx]  = s ? 0.f : v;
        s1t[idx] = s ? (unsigned char)1 : (unsigned char)0;
    }
}

// ---------------------------------------------------------------------------
// k_temp (per t): 3x3 conv 128->2 + BN + LIF(vtm); writes x_out spikes (float)
// grid (64 row-pairs, B), block 256 = 2 rows x 128 cols.  s1 tile in LDS (64KB).
// ---------------------------------------------------------------------------
__global__ __launch_bounds__(256)
void k_temp(const unsigned char* __restrict__ s1t, const float* __restrict__ wt,
            const float* __restrict__ g, const float* __restrict__ bb,
            const float* __restrict__ mm, const float* __restrict__ vv,
            float* __restrict__ vtm, float* __restrict__ xout) {
    __shared__ unsigned char sl[128 * 4 * 128];   // [ic][4 rows][128 cols] = 64KB
    const int tid = threadIdx.x;
    const int b   = blockIdx.y;
    const int y0  = blockIdx.x * 2;

    for (int i = tid; i < 16384; i += 256) {      // stage as dwords
        int e = i * 4;
        int ic = e >> 9, r = (e >> 7) & 3, xb = e & 127;
        int gy = y0 - 1 + r;
        unsigned int w = 0;
        if (gy >= 0 && gy < 128)
            w = *(const unsigned int*)(s1t + ((b * 128 + ic) << 14) + (gy << 7) + xb);
        ((unsigned int*)sl)[i] = w;
    }
    __syncthreads();

    const int row = tid >> 7, x = tid & 127;
    float a0 = 0.f, a1 = 0.f;
    for (int ic = 0; ic < 128; ++ic) {
#pragma unroll
        for (int ky = 0; ky < 3; ++ky) {
            const unsigned char* rp = &sl[(ic * 4 + row + ky) * 128];
#pragma unroll
            for (int kx = 0; kx < 3; ++kx) {
                int xx = x - 1 + kx;
                float f = 0.f;
                if (xx >= 0 && xx < 128) f = (float)rp[xx];
                a0 = fmaf(wt[ic * 9 + ky * 3 + kx],        f, a0);
                a1 = fmaf(wt[1152 + ic * 9 + ky * 3 + kx], f, a1);
            }
        }
    }
    const int gy = y0 + row;
#pragma unroll
    for (int oc = 0; oc < 2; ++oc) {
        float acc = (oc == 0) ? a0 : a1;
        float sc = g[oc] / sqrtf(vv[oc] + 1e-5f);
        float y  = (acc - mm[oc]) * sc + bb[oc];
        int idx = ((b * 2 + oc) << 14) + (gy << 7) + x;
        float v = vtm[idx];
        v = v + (y - v) * 0.5f;
        bool s = (v >= 1.0f);
        vtm[idx]  = s ? 0.f : v;
        xout[idx] = s ? 1.0f : 0.f;
    }
}

// ---------------------------------------------------------------------------
// k_big: fused  [3x3 conv 128->256 + BN + LIF]  and  [1x1 conv 128->256 + BN
// + LIF]  with the t=0..3 loop inside (LIF states va/vr live in registers),
// out = spike_a + spike_r.
// grid (4 Wtiles, 16 Htiles, 8 octiles * 4 b), block 256.
// Per block: 32 oc x (8 rows x 32 cols); thread: 4 oc x 8 px.
// ---------------------------------------------------------------------------
__global__ __launch_bounds__(256)
void k_big(const unsigned char* __restrict__ s1, const float* __restrict__ wt1,
           const float* __restrict__ wrt,
           const float* __restrict__ g1, const float* __restrict__ b1,
           const float* __restrict__ m1, const float* __restrict__ v1,
           const float* __restrict__ gr, const float* __restrict__ br,
           const float* __restrict__ mr, const float* __restrict__ vrr,
           float* __restrict__ out) {
    __shared__ float slds[16 * 10 * 36];   // [ic][10 rows][36 cols], 23.0 KB
    __shared__ float wlds[144 * 32];       // [ic*9+tap][32 oc],      18.4 KB
    __shared__ float wrlds[16 * 32];       // [ic][32 oc],             2.0 KB

    const int tid = threadIdx.x;
    const int gx0 = blockIdx.x * 32;
    const int gy0 = blockIdx.y * 8;
    const int oct = blockIdx.z >> 2;
    const int b   = blockIdx.z & 3;
    const int oc0 = oct * 32;
    const int ocg = tid >> 5;              // 8 groups of 4 oc
    const int pxg = tid & 31;              // 32 px-groups of 8 px
    const int prow = pxg >> 2;
    const int colbase = (pxg & 3) * 8;

    float va[4][8], vres[4][8];
#pragma unroll
    for (int i = 0; i < 4; ++i)
#pragma unroll
        for (int j = 0; j < 8; ++j) { va[i][j] = 0.f; vres[i][j] = 0.f; }

#pragma unroll 1
    for (int t = 0; t < 4; ++t) {
        const unsigned char* s1t = s1 + (size_t)t * (4 * 128 * HW);
        float acc[4][8], accr[4][8];
#pragma unroll
        for (int i = 0; i < 4; ++i)
#pragma unroll
            for (int j = 0; j < 8; ++j) { acc[i][j] = 0.f; accr[i][j] = 0.f; }

#pragma unroll 1
        for (int icc = 0; icc < 8; ++icc) {
            const int ic0 = icc * 16;
            // ---- stage s tile: 16 ic x 10 rows x 34 cols (stride 36) ----
            for (int i = tid; i < 5440; i += 256) {
                int ic = i / 340, rem = i % 340;
                int r = rem / 34, c = rem % 34;
                int gy = gy0 - 1 + r, gx = gx0 - 1 + c;
                float val = 0.f;
                if (gy >= 0 && gy < 128 && gx >= 0 && gx < 128)
                    val = (float)s1t[((b * 128 + ic0 + ic) << 14) + (gy << 7) + gx];
                slds[(ic * 10 + r) * 36 + c] = val;
            }
            // ---- stage w1 chunk: [144][32] (coalesced from wt1) ----
            for (int i = tid; i < 1152; i += 256) {
                int e = i * 4;
                int r = e >> 5, oci = e & 31;
                *(float4*)&wlds[e] = *(const float4*)&wt1[(ic0 * 9 + r) * 256 + oc0 + oci];
            }
            // ---- stage w_res chunk: [16][32] ----
            if (tid < 128) {
                int e = tid * 4;
                int ic = e >> 5, oci = e & 31;
                *(float4*)&wrlds[e] = *(const float4*)&wrt[(ic0 + ic) * 256 + oc0 + oci];
            }
            __syncthreads();

#pragma unroll 2
            for (int ic = 0; ic < 16; ++ic) {
#pragma unroll
                for (int ky = 0; ky < 3; ++ky) {
                    const float* srow = &slds[(ic * 10 + prow + ky) * 36 + colbase];
                    float4 aa  = *(const float4*)srow;
                    float4 bb4 = *(const float4*)(srow + 4);
                    float w10[10];
                    w10[0] = aa.x;  w10[1] = aa.y;  w10[2] = aa.z;  w10[3] = aa.w;
                    w10[4] = bb4.x; w10[5] = bb4.y; w10[6] = bb4.z; w10[7] = bb4.w;
                    w10[8] = srow[8]; w10[9] = srow[9];
#pragma unroll
                    for (int kx = 0; kx < 3; ++kx) {
                        float4 wv = *(const float4*)&wlds[(ic * 9 + ky * 3 + kx) * 32 + ocg * 4];
                        float wv4[4] = {wv.x, wv.y, wv.z, wv.w};
#pragma unroll
                        for (int i = 0; i < 4; ++i)
#pragma unroll
                            for (int j = 0; j < 8; ++j)
                                acc[i][j] = fmaf(wv4[i], w10[kx + j], acc[i][j]);
                    }
                    if (ky == 1) {   // 1x1 res conv shares the center window
                        float4 wr4 = *(const float4*)&wrlds[ic * 32 + ocg * 4];
                        float wr_[4] = {wr4.x, wr4.y, wr4.z, wr4.w};
#pragma unroll
                        for (int i = 0; i < 4; ++i)
#pragma unroll
                            for (int j = 0; j < 8; ++j)
                                accr[i][j] = fmaf(wr_[i], w10[1 + j], accr[i][j]);
                    }
                }
            }
            __syncthreads();
        }

        // ---- epilogue for this t: BN + LIF (both paths), write out ----
#pragma unroll
        for (int i = 0; i < 4; ++i) {
            const int oc = oc0 + ocg * 4 + i;
            float sca = g1[oc] / sqrtf(v1[oc] + 1e-5f);
            float scr = gr[oc] / sqrtf(vrr[oc] + 1e-5f);
            float m1v = m1[oc], b1v = b1[oc], mrv = mr[oc], brv = br[oc];
            float* op = out + ((size_t)((t * 4 + b) * 256 + oc) << 14)
                            + ((gy0 + prow) << 7) + gx0 + colbase;
#pragma unroll
            for (int j = 0; j < 8; ++j) {
                float ha = (acc[i][j] - m1v) * sca + b1v;
                float v = va[i][j];
                v = v + (ha - v) * 0.5f;
                float sa = (v >= 1.0f) ? 1.f : 0.f;
                va[i][j] = (v >= 1.0f) ? 0.f : v;

                float hr = (accr[i][j] - mrv) * scr + brv;
                float w = vres[i][j];
                w = w + (hr - w) * 0.5f;
                float sr = (w >= 1.0f) ? 1.f : 0.f;
                vres[i][j] = (w >= 1.0f) ? 0.f : w;

                op[j] = sa + sr;
            }
        }
    }
}

// ---------------------------------------------------------------------------
// Workspace layout (bytes):
//   s1    @ 0          33,554,432   (uint8 spikes [T][B][128][H][W])
//   vp    @ 33,554,432 33,554,432   (float  [B][128][H][W])
//   vtm   @ 67,108,864    524,288   (float  [B][2][H][W])
//   xout  @ 67,633,152    524,288   (float  [B][2][H][W])
//   wt1   @ 68,157,440  1,179,648   (float  [1152][256])
//   wrt   @ 69,337,088    131,072   (float  [128][256])
// total ≈ 69.5 MB
// ---------------------------------------------------------------------------
extern "C" void kernel_launch(void* const* d_in, const int* in_sizes, int n_in,
                              void* d_out, int out_size, void* d_ws, size_t ws_size,
                              hipStream_t stream) {
    const float* x      = (const float*)d_in[0];
    const float* w_proj = (const float*)d_in[1];
    const float* g0 = (const float*)d_in[2];
    const float* b0 = (const float*)d_in[3];
    const float* m0 = (const float*)d_in[4];
    const float* v0 = (const float*)d_in[5];
    const float* w_temp = (const float*)d_in[6];
    const float* gt = (const float*)d_in[7];
    const float* bt = (const float*)d_in[8];
    const float* mt = (const float*)d_in[9];
    const float* vt = (const float*)d_in[10];
    const float* w1 = (const float*)d_in[11];
    const float* g1 = (const float*)d_in[12];
    const float* b1 = (const float*)d_in[13];
    const float* m1 = (const float*)d_in[14];
    const float* v1 = (const float*)d_in[15];
    const float* w_res = (const float*)d_in[16];
    const float* gr = (const float*)d_in[17];
    const float* br = (const float*)d_in[18];
    const float* mr = (const float*)d_in[19];
    const float* vr = (const float*)d_in[20];

    char* ws = (char*)d_ws;
    unsigned char* s1 = (unsigned char*)ws;
    float* vp   = (float*)(ws + 33554432);
    float* vtm  = (float*)(ws + 67108864);
    float* xout = (float*)(ws + 67633152);
    float* wt1  = (float*)(ws + 68157440);
    float* wrt  = (float*)(ws + 69337088);

    // zero the LIF states + recurrent x_out (ws is poisoned before each call)
    hipMemsetAsync(ws + 33554432, 0, 34603008, stream);

    k_reorder<<<dim3(1152), dim3(256), 0, stream>>>(w1, w_res, wt1, wrt);

    for (int t = 0; t < 4; ++t) {
        const float* xt = x + (size_t)t * 4 * 2 * HW;
        unsigned char* s1t = s1 + (size_t)t * 4 * 128 * HW;
        k_proj<<<dim3(4, 16, 16), dim3(256), 0, stream>>>(
            xt, xout, w_proj, g0, b0, m0, v0, vp, s1t);
        k_temp<<<dim3(64, 4), dim3(256), 0, stream>>>(
            s1t, w_temp, gt, bt, mt, vt, vtm, xout);
    }

    k_big<<<dim3(4, 16, 32), dim3(256), 0, stream>>>(
        s1, wt1, wrt, g1, b1, m1, v1, gr, br, mr, vr, (float*)d_out);
}

// Round 3
// 2073.733 us; speedup vs baseline: 2.5491x; 2.5491x over previous
//
#include <hip/hip_runtime.h>
#include <math.h>

// Problem constants: T=4, B=4, C=2, H=W=128 (HW=16384), E=256, half=128.
#define HW 16384

typedef __attribute__((ext_vector_type(8))) short short8;
typedef __attribute__((ext_vector_type(4))) float f32x4;

__device__ inline unsigned short f2bf(float f) {
    unsigned int u = __float_as_uint(f);
    u += 0x7FFF + ((u >> 16) & 1);          // RNE
    return (unsigned short)(u >> 16);
}
__device__ inline float bf2f(unsigned short h) {
    return __uint_as_float(((unsigned int)h) << 16);
}

// ---------------------------------------------------------------------------
// k_reorder3: 3-way EXACT bf16 split of w1 and w_res into MFMA-B-friendly
// layout: w1 -> plane[kb 4][tap 9][quad 4][n 256][j 8], ic = kb*32+quad*8+j.
// w_res -> plane[kb 4][quad 4][n 256][j 8].  hi+mid+lo == w bit-exactly
// (8+8+8 mantissa bits with exact-residual property covers fp32's 24).
// ---------------------------------------------------------------------------
__global__ __launch_bounds__(256)
void k_reorder3(const float* __restrict__ w1, const float* __restrict__ wres,
                short* __restrict__ whi, short* __restrict__ wmid, short* __restrict__ wlo,
                short* __restrict__ rhi, short* __restrict__ rmid, short* __restrict__ rlo) {
    int i = blockIdx.x * 256 + threadIdx.x;
    if (i < 294912) {                 // 256 oc * 128 ic * 9 taps
        int n = i / 1152, rem = i % 1152;
        int ic = rem / 9, tap = rem % 9;
        float wv = w1[i];
        unsigned short h = f2bf(wv);
        float r1 = wv - bf2f(h);
        unsigned short m = f2bf(r1);
        float r2 = r1 - bf2f(m);
        unsigned short lo = f2bf(r2);
        int kb = ic >> 5, q = (ic >> 3) & 3, j = ic & 7;
        size_t f = ((((size_t)(kb * 9 + tap)) * 4 + q) * 256 + n) * 8 + j;
        whi[f] = (short)h; wmid[f] = (short)m; wlo[f] = (short)lo;
    }
    if (i < 32768) {                  // 256 oc * 128 ic
        int n = i >> 7, ic = i & 127;
        float wv = wres[i];
        unsigned short h = f2bf(wv);
        float r1 = wv - bf2f(h);
        unsigned short m = f2bf(r1);
        float r2 = r1 - bf2f(m);
        unsigned short lo = f2bf(r2);
        int kb = ic >> 5, q = (ic >> 3) & 3, j = ic & 7;
        size_t f = (((size_t)kb * 4 + q) * 256 + n) * 8 + j;
        rhi[f] = (short)h; rmid[f] = (short)m; rlo[f] = (short)lo;
    }
}

// ---------------------------------------------------------------------------
// k_proj (per t): x_in = x[t] + x_out;  3x3 conv 2->128 + BN + LIF(vp)
// ---------------------------------------------------------------------------
__global__ __launch_bounds__(256)
void k_proj(const float* __restrict__ xt, const float* __restrict__ xout,
            const float* __restrict__ wp,
            const float* __restrict__ g, const float* __restrict__ bb,
            const float* __restrict__ mm, const float* __restrict__ vv,
            float* __restrict__ vp, unsigned char* __restrict__ s1t) {
    __shared__ float xin[2 * 10 * 36];
    const int tid = threadIdx.x;
    const int b   = blockIdx.z >> 2;
    const int ocq = blockIdx.z & 3;
    const int gy0 = blockIdx.y * 8, gx0 = blockIdx.x * 32;

    for (int i = tid; i < 680; i += 256) {
        int ch = i / 340, rem = i % 340;
        int r = rem / 34, c = rem % 34;
        int gy = gy0 - 1 + r, gx = gx0 - 1 + c;
        float val = 0.f;
        if (gy >= 0 && gy < 128 && gx >= 0 && gx < 128) {
            int idx = ((b * 2 + ch) << 14) + (gy << 7) + gx;
            val = xt[idx] + xout[idx];
        }
        xin[(ch * 10 + r) * 36 + c] = val;
    }
    __syncthreads();

    const int prow = tid >> 5, pcol = tid & 31;
    float xw[2][3][3];
#pragma unroll
    for (int ch = 0; ch < 2; ++ch)
#pragma unroll
        for (int ky = 0; ky < 3; ++ky)
#pragma unroll
            for (int kx = 0; kx < 3; ++kx)
                xw[ch][ky][kx] = xin[(ch * 10 + prow + ky) * 36 + pcol + kx];

    const int pix = ((gy0 + prow) << 7) + gx0 + pcol;
    const int oc_beg = ocq * 32;
    for (int oc = oc_beg; oc < oc_beg + 32; ++oc) {
        float acc = 0.f;
#pragma unroll
        for (int ch = 0; ch < 2; ++ch)
#pragma unroll
            for (int ky = 0; ky < 3; ++ky)
#pragma unroll
                for (int kx = 0; kx < 3; ++kx)
                    acc = fmaf(wp[((oc * 2 + ch) * 3 + ky) * 3 + kx], xw[ch][ky][kx], acc);
        float sc = g[oc] / sqrtf(vv[oc] + 1e-5f);
        float h  = (acc - mm[oc]) * sc + bb[oc];
        int idx = ((b * 128 + oc) << 14) + pix;
        float v = vp[idx];
        v = v + (h - v) * 0.5f;
        bool s = (v >= 1.0f);
        vp[idx]  = s ? 0.f : v;
        s1t[idx] = s ? (unsigned char)1 : (unsigned char)0;
    }
}

// ---------------------------------------------------------------------------
// k_temp (per t): 3x3 conv 128->2 + BN + LIF(vtm); writes x_out spikes (float)
// ---------------------------------------------------------------------------
__global__ __launch_bounds__(256)
void k_temp(const unsigned char* __restrict__ s1t, const float* __restrict__ wt,
            const float* __restrict__ g, const float* __restrict__ bb,
            const float* __restrict__ mm, const float* __restrict__ vv,
            float* __restrict__ vtm, float* __restrict__ xout) {
    __shared__ unsigned char sl[128 * 4 * 128];
    const int tid = threadIdx.x;
    const int b   = blockIdx.y;
    const int y0  = blockIdx.x * 2;

    for (int i = tid; i < 16384; i += 256) {
        int e = i * 4;
        int ic = e >> 9, r = (e >> 7) & 3, xb = e & 127;
        int gy = y0 - 1 + r;
        unsigned int w = 0;
        if (gy >= 0 && gy < 128)
            w = *(const unsigned int*)(s1t + ((b * 128 + ic) << 14) + (gy << 7) + xb);
        ((unsigned int*)sl)[i] = w;
    }
    __syncthreads();

    const int row = tid >> 7, x = tid & 127;
    float a0 = 0.f, a1 = 0.f;
    for (int ic = 0; ic < 128; ++ic) {
#pragma unroll
        for (int ky = 0; ky < 3; ++ky) {
            const unsigned char* rp = &sl[(ic * 4 + row + ky) * 128];
#pragma unroll
            for (int kx = 0; kx < 3; ++kx) {
                int xx = x - 1 + kx;
                float f = 0.f;
                if (xx >= 0 && xx < 128) f = (float)rp[xx];
                a0 = fmaf(wt[ic * 9 + ky * 3 + kx],        f, a0);
                a1 = fmaf(wt[1152 + ic * 9 + ky * 3 + kx], f, a1);
            }
        }
    }
    const int gy = y0 + row;
#pragma unroll
    for (int oc = 0; oc < 2; ++oc) {
        float acc = (oc == 0) ? a0 : a1;
        float sc = g[oc] / sqrtf(vv[oc] + 1e-5f);
        float y  = (acc - mm[oc]) * sc + bb[oc];
        int idx = ((b * 2 + oc) << 14) + (gy << 7) + x;
        float v = vtm[idx];
        v = v + (y - v) * 0.5f;
        bool s = (v >= 1.0f);
        vtm[idx]  = s ? 0.f : v;
        xout[idx] = s ? 1.0f : 0.f;
    }
}

// ---------------------------------------------------------------------------
// k_big: 3x3 conv 128->256 as implicit GEMM with mfma_f32_16x16x32_bf16,
// 3-way exact bf16 weight split, + BN + LIF over t (state in registers).
// K = 128 ic * 9 taps = 1152 -> kb in [0,4) blocks of 32 ic  x 9 taps
// (ROUND-2 BUG: kb<8 overran the 46080B LDS tile AND the whi plane into
// wmid — xa path garbage. 4 kb * 32 ic = 128 ic is the correct count.)
// Block: 256 thr = 4 waves (2x2), tile 128 px (8 rows x 16 cols) x 64 oc.
// grid (4 oc-tiles, 512 px-tiles = b*128 + ry*8 + cx)
// ---------------------------------------------------------------------------
__global__ __launch_bounds__(256)
void k_big(const unsigned char* __restrict__ s1,
           const short* __restrict__ whi, const short* __restrict__ wmid,
           const short* __restrict__ wlo,
           const float* __restrict__ g1, const float* __restrict__ b1,
           const float* __restrict__ m1, const float* __restrict__ v1,
           float* __restrict__ out) {
    __shared__ __align__(16) char lds[46080];     // s-tile 16*180*16B; reused as 64*132 f32
    float* tr = (float*)lds;

    const int tid = threadIdx.x;
    const int oc0 = blockIdx.x * 64;
    const int y = blockIdx.y;
    const int b = y >> 7, ry = (y >> 3) & 15, cx = y & 7;
    const int gy0 = ry * 8, gx0 = cx * 16;

    const int w  = tid >> 6, l = tid & 63;
    const int q  = l >> 4,  ln = l & 15;
    const int wm = w >> 1,  wn = w & 1;

    float sca[2], mm_[2], bb_[2];
#pragma unroll
    for (int nt = 0; nt < 2; ++nt) {
        int oc = oc0 + wn * 32 + nt * 16 + ln;
        sca[nt] = g1[oc] / sqrtf(v1[oc] + 1e-5f);
        mm_[nt] = m1[oc]; bb_[nt] = b1[oc];
    }

    const size_t bofs = ((size_t)q * 256 + oc0 + wn * 32 + ln) * 8;
    const int abase = q * 2880 + wm * 1152 + ln * 16;   // bytes into lds

    float va[4][2][4];
#pragma unroll
    for (int i = 0; i < 4; ++i)
#pragma unroll
        for (int nt = 0; nt < 2; ++nt)
#pragma unroll
            for (int rg = 0; rg < 4; ++rg) va[i][nt][rg] = 0.f;

#pragma unroll 1
    for (int t = 0; t < 4; ++t) {
        const unsigned char* s1t = s1 + (size_t)t * (4 * 128 * HW) + ((size_t)b << 21);

        // ---- stage spike window: [icb 16][p 180][8 ic] bf16 (0/1) ----
        for (int cc = tid; cc < 2880; cc += 256) {
            int icb = cc / 180, p = cc - icb * 180;
            int r = p / 18, c = p - r * 18;
            int gy = gy0 - 1 + r, gx = gx0 - 1 + c;
            uint4 pk = make_uint4(0u, 0u, 0u, 0u);
            if (gy >= 0 && gy < 128 && gx >= 0 && gx < 128) {
                const unsigned char* sp = s1t + ((size_t)(icb * 8) << 14) + (gy << 7) + gx;
                unsigned int v0 = sp[0]        ? 0x3F80u : 0u;
                unsigned int v1_ = sp[1 << 14] ? 0x3F80u : 0u;
                unsigned int v2 = sp[2 << 14]  ? 0x3F80u : 0u;
                unsigned int v3 = sp[3 << 14]  ? 0x3F80u : 0u;
                unsigned int v4 = sp[4 << 14]  ? 0x3F80u : 0u;
                unsigned int v5 = sp[5 << 14]  ? 0x3F80u : 0u;
                unsigned int v6 = sp[6 << 14]  ? 0x3F80u : 0u;
                unsigned int v7 = sp[7 << 14]  ? 0x3F80u : 0u;
                pk = make_uint4(v0 | (v1_ << 16), v2 | (v3 << 16),
                                v4 | (v5 << 16), v6 | (v7 << 16));
            }
            ((uint4*)lds)[cc] = pk;
        }
        __syncthreads();

        f32x4 acc[4][2];
#pragma unroll
        for (int i = 0; i < 4; ++i)
#pragma unroll
            for (int nt = 0; nt < 2; ++nt) acc[i][nt] = (f32x4)(0.f);

        const short* bh = whi  + bofs;
        const short* bm = wmid + bofs;
        const short* bl = wlo  + bofs;
        int ab = abase;

#pragma unroll 1
        for (int kb = 0; kb < 4; ++kb) {            // 4 * 32 ic = 128 ic
#pragma unroll
            for (int ky = 0; ky < 3; ++ky) {
#pragma unroll
                for (int kx = 0; kx < 3; ++kx) {
                    short8 A[4];
#pragma unroll
                    for (int i = 0; i < 4; ++i)
                        A[i] = *(const short8*)(lds + ab + (i + ky) * 288 + kx * 16);
                    short8 BH[2], BM[2], BL[2];
#pragma unroll
                    for (int nt = 0; nt < 2; ++nt) {
                        BH[nt] = *(const short8*)(bh + nt * 128);
                        BM[nt] = *(const short8*)(bm + nt * 128);
                        BL[nt] = *(const short8*)(bl + nt * 128);
                    }
#pragma unroll
                    for (int i = 0; i < 4; ++i)
#pragma unroll
                        for (int nt = 0; nt < 2; ++nt) {
                            acc[i][nt] = __builtin_amdgcn_mfma_f32_16x16x32_bf16(A[i], BH[nt], acc[i][nt], 0, 0, 0);
                            acc[i][nt] = __builtin_amdgcn_mfma_f32_16x16x32_bf16(A[i], BM[nt], acc[i][nt], 0, 0, 0);
                            acc[i][nt] = __builtin_amdgcn_mfma_f32_16x16x32_bf16(A[i], BL[nt], acc[i][nt], 0, 0, 0);
                        }
                    bh += 8192; bm += 8192; bl += 8192;
                }
            }
            ab += 11520;
        }
        __syncthreads();   // done reading s-tile; lds becomes transpose buffer

        // ---- BN + LIF + transpose spikes into [oc 64][px 128] (pad 132) ----
#pragma unroll
        for (int i = 0; i < 4; ++i)
#pragma unroll
            for (int nt = 0; nt < 2; ++nt) {
                float ofs[4];
#pragma unroll
                for (int rg = 0; rg < 4; ++rg) {
                    float h = (acc[i][nt][rg] - mm_[nt]) * sca[nt] + bb_[nt];
                    float v = va[i][nt][rg];
                    v = v + (h - v) * 0.5f;
                    bool s = (v >= 1.0f);
                    va[i][nt][rg] = s ? 0.f : v;
                    ofs[rg] = s ? 1.f : 0.f;
                }
                float* dst = &tr[(wn * 32 + nt * 16 + ln) * 132 + (wm * 4 + i) * 16 + q * 4];
                dst[0] = ofs[0]; dst[1] = ofs[1]; dst[2] = ofs[2]; dst[3] = ofs[3];
            }
        __syncthreads();

        // ---- coalesced store ----
        const size_t obase = ((size_t)((t * 4 + b) * 256 + oc0)) << 14;
#pragma unroll
        for (int rr = 0; rr < 16; ++rr) {
            int ocr = w * 16 + rr;
#pragma unroll
            for (int hf = 0; hf < 2; ++hf) {
                int px = hf * 64 + l;
                out[obase + ((size_t)ocr << 14) + ((gy0 + (px >> 4)) << 7) + gx0 + (px & 15)]
                    = tr[ocr * 132 + px];
            }
        }
        __syncthreads();   // before next t's staging
    }
}

// ---------------------------------------------------------------------------
// k_res: 1x1 conv 128->256 (MFMA, 3-way split) + BN + LIF over t; out += spike.
// Same tiling as k_big, K=128 only (center pixel, no halo).
// ---------------------------------------------------------------------------
__global__ __launch_bounds__(256)
void k_res(const unsigned char* __restrict__ s1,
           const short* __restrict__ rhi, const short* __restrict__ rmid,
           const short* __restrict__ rlo,
           const float* __restrict__ gr, const float* __restrict__ br,
           const float* __restrict__ mr, const float* __restrict__ vr,
           float* __restrict__ out) {
    __shared__ __align__(16) char lds[33792];     // max(16*128*16B, 64*132*4B)
    float* tr = (float*)lds;

    const int tid = threadIdx.x;
    const int oc0 = blockIdx.x * 64;
    const int y = blockIdx.y;
    const int b = y >> 7, ry = (y >> 3) & 15, cx = y & 7;
    const int gy0 = ry * 8, gx0 = cx * 16;

    const int w  = tid >> 6, l = tid & 63;
    const int q  = l >> 4,  ln = l & 15;
    const int wm = w >> 1,  wn = w & 1;

    float sca[2], mm_[2], bb_[2];
#pragma unroll
    for (int nt = 0; nt < 2; ++nt) {
        int oc = oc0 + wn * 32 + nt * 16 + ln;
        sca[nt] = gr[oc] / sqrtf(vr[oc] + 1e-5f);
        mm_[nt] = mr[oc]; bb_[nt] = br[oc];
    }

    const size_t bofs = ((size_t)q * 256 + oc0 + wn * 32 + ln) * 8;
    const int ab0 = q * 2048 + wm * 1024 + ln * 16;   // bytes

    float va[4][2][4];
#pragma unroll
    for (int i = 0; i < 4; ++i)
#pragma unroll
        for (int nt = 0; nt < 2; ++nt)
#pragma unroll
            for (int rg = 0; rg < 4; ++rg) va[i][nt][rg] = 0.f;

#pragma unroll 1
    for (int t = 0; t < 4; ++t) {
        const unsigned char* s1t = s1 + (size_t)t * (4 * 128 * HW) + ((size_t)b << 21);

        // stage center tile: [icb 16][p 128][8 ic]
        for (int cc = tid; cc < 2048; cc += 256) {
            int icb = cc >> 7, p = cc & 127;
            int gy = gy0 + (p >> 4), gx = gx0 + (p & 15);
            const unsigned char* sp = s1t + ((size_t)(icb * 8) << 14) + (gy << 7) + gx;
            unsigned int v0 = sp[0]        ? 0x3F80u : 0u;
            unsigned int v1_ = sp[1 << 14] ? 0x3F80u : 0u;
            unsigned int v2 = sp[2 << 14]  ? 0x3F80u : 0u;
            unsigned int v3 = sp[3 << 14]  ? 0x3F80u : 0u;
            unsigned int v4 = sp[4 << 14]  ? 0x3F80u : 0u;
            unsigned int v5 = sp[5 << 14]  ? 0x3F80u : 0u;
            unsigned int v6 = sp[6 << 14]  ? 0x3F80u : 0u;
            unsigned int v7 = sp[7 << 14]  ? 0x3F80u : 0u;
            ((uint4*)lds)[cc] = make_uint4(v0 | (v1_ << 16), v2 | (v3 << 16),
                                           v4 | (v5 << 16), v6 | (v7 << 16));
        }
        __syncthreads();

        f32x4 acc[4][2];
#pragma unroll
        for (int i = 0; i < 4; ++i)
#pragma unroll
            for (int nt = 0; nt < 2; ++nt) acc[i][nt] = (f32x4)(0.f);

#pragma unroll
        for (int kb = 0; kb < 4; ++kb) {
            short8 A[4];
#pragma unroll
            for (int i = 0; i < 4; ++i)
                A[i] = *(const short8*)(lds + ab0 + kb * 8192 + i * 256);
            const short* bh = rhi + bofs + (size_t)kb * 8192;
            const short* bm = rmid + bofs + (size_t)kb * 8192;
            const short* bl = rlo + bofs + (size_t)kb * 8192;
#pragma unroll
            for (int nt = 0; nt < 2; ++nt) {
                short8 BH = *(const short8*)(bh + nt * 128);
                short8 BM = *(const short8*)(bm + nt * 128);
                short8 BL = *(const short8*)(bl + nt * 128);
#pragma unroll
                for (int i = 0; i < 4; ++i) {
                    acc[i][nt] = __builtin_amdgcn_mfma_f32_16x16x32_bf16(A[i], BH, acc[i][nt], 0, 0, 0);
                    acc[i][nt] = __builtin_amdgcn_mfma_f32_16x16x32_bf16(A[i], BM, acc[i][nt], 0, 0, 0);
                    acc[i][nt] = __builtin_amdgcn_mfma_f32_16x16x32_bf16(A[i], BL, acc[i][nt], 0, 0, 0);
                }
            }
        }
        __syncthreads();

#pragma unroll
        for (int i = 0; i < 4; ++i)
#pragma unroll
            for (int nt = 0; nt < 2; ++nt) {
                float ofs[4];
#pragma unroll
                for (int rg = 0; rg < 4; ++rg) {
                    float h = (acc[i][nt][rg] - mm_[nt]) * sca[nt] + bb_[nt];
                    float v = va[i][nt][rg];
                    v = v + (h - v) * 0.5f;
                    bool s = (v >= 1.0f);
                    va[i][nt][rg] = s ? 0.f : v;
                    ofs[rg] = s ? 1.f : 0.f;
                }
                float* dst = &tr[(wn * 32 + nt * 16 + ln) * 132 + (wm * 4 + i) * 16 + q * 4];
                dst[0] = ofs[0]; dst[1] = ofs[1]; dst[2] = ofs[2]; dst[3] = ofs[3];
            }
        __syncthreads();

        const size_t obase = ((size_t)((t * 4 + b) * 256 + oc0)) << 14;
#pragma unroll
        for (int rr = 0; rr < 16; ++rr) {
            int ocr = w * 16 + rr;
#pragma unroll
            for (int hf = 0; hf < 2; ++hf) {
                int px = hf * 64 + l;
                size_t o = obase + ((size_t)ocr << 14) + ((gy0 + (px >> 4)) << 7) + gx0 + (px & 15);
                out[o] += tr[ocr * 132 + px];
            }
        }
        __syncthreads();
    }
}

// ---------------------------------------------------------------------------
// Workspace layout (bytes):
//   s1    @ 0          33,554,432  (uint8 spikes [T][B][128][H][W])
//   vp    @ 33,554,432 33,554,432  (float LIF state; DEAD after t-loop ->
//     weight planes overlap it:  whi @33,554,432 (589,824), wmid, wlo,
//     rhi @35,323,904 (65,536), rmid, rlo  — end 35,520,512)
//   vtm   @ 67,108,864    524,288
//   xout  @ 67,633,152    524,288     total = 68,157,440
// ---------------------------------------------------------------------------
extern "C" void kernel_launch(void* const* d_in, const int* in_sizes, int n_in,
                              void* d_out, int out_size, void* d_ws, size_t ws_size,
                              hipStream_t stream) {
    const float* x      = (const float*)d_in[0];
    const float* w_proj = (const float*)d_in[1];
    const float* g0 = (const float*)d_in[2];
    const float* b0 = (const float*)d_in[3];
    const float* m0 = (const float*)d_in[4];
    const float* v0 = (const float*)d_in[5];
    const float* w_temp = (const float*)d_in[6];
    const float* gt = (const float*)d_in[7];
    const float* bt = (const float*)d_in[8];
    const float* mt = (const float*)d_in[9];
    const float* vt = (const float*)d_in[10];
    const float* w1 = (const float*)d_in[11];
    const float* g1 = (const float*)d_in[12];
    const float* b1 = (const float*)d_in[13];
    const float* m1 = (const float*)d_in[14];
    const float* v1 = (const float*)d_in[15];
    const float* w_res = (const float*)d_in[16];
    const float* gr = (const float*)d_in[17];
    const float* br = (const float*)d_in[18];
    const float* mr = (const float*)d_in[19];
    const float* vr = (const float*)d_in[20];

    char* ws = (char*)d_ws;
    unsigned char* s1 = (unsigned char*)ws;
    float* vp   = (float*)(ws + 33554432);
    float* vtm  = (float*)(ws + 67108864);
    float* xout = (float*)(ws + 67633152);
    short* whi  = (short*)(ws + 33554432);   // overlaps vp (dead after t-loop)
    short* wmid = (short*)(ws + 34144256);
    short* wlo  = (short*)(ws + 34734080);
    short* rhi  = (short*)(ws + 35323904);
    short* rmid = (short*)(ws + 35389440);
    short* rlo  = (short*)(ws + 35454976);

    // zero LIF states + recurrent x_out
    hipMemsetAsync(ws + 33554432, 0, 34603008, stream);

    for (int t = 0; t < 4; ++t) {
        const float* xt = x + (size_t)t * 4 * 2 * HW;
        unsigned char* s1t = s1 + (size_t)t * 4 * 128 * HW;
        k_proj<<<dim3(4, 16, 16), dim3(256), 0, stream>>>(
            xt, xout, w_proj, g0, b0, m0, v0, vp, s1t);
        k_temp<<<dim3(64, 4), dim3(256), 0, stream>>>(
            s1t, w_temp, gt, bt, mt, vt, vtm, xout);
    }

    // weights reorder AFTER the t-loop (vp is dead, planes overlap it)
    k_reorder3<<<dim3(1152), dim3(256), 0, stream>>>(
        w1, w_res, whi, wmid, wlo, rhi, rmid, rlo);

    k_big<<<dim3(4, 512), dim3(256), 0, stream>>>(
        s1, whi, wmid, wlo, g1, b1, m1, v1, (float*)d_out);
    k_res<<<dim3(4, 512), dim3(256), 0, stream>>>(
        s1, rhi, rmid, rlo, gr, br, mr, vr, (float*)d_out);
}

// Round 4
// 1278.118 us; speedup vs baseline: 4.1359x; 1.6225x over previous
//
#include <hip/hip_runtime.h>
#include <math.h>

// Problem constants: T=4, B=4, C=2, H=W=128 (HW=16384), E=256, half=128.
#define HW 16384

typedef __attribute__((ext_vector_type(8))) short short8;
typedef __attribute__((ext_vector_type(4))) float f32x4;

__device__ inline unsigned short f2bf(float f) {
    unsigned int u = __float_as_uint(f);
    u += 0x7FFF + ((u >> 16) & 1);          // RNE
    return (unsigned short)(u >> 16);
}
__device__ inline float bf2f(unsigned short h) {
    return __uint_as_float(((unsigned int)h) << 16);
}

// ---------------------------------------------------------------------------
// k_reorder3: 3-way EXACT bf16 split of w1 and w_res into MFMA-B layout:
// w1 -> plane[kb 4][tap 9][quad 4][n 256][j 8], ic = kb*32+quad*8+j.
// w_res -> plane[kb 4][quad 4][n 256][j 8].  hi+mid+lo == w bit-exactly.
// ---------------------------------------------------------------------------
__global__ __launch_bounds__(256)
void k_reorder3(const float* __restrict__ w1, const float* __restrict__ wres,
                short* __restrict__ whi, short* __restrict__ wmid, short* __restrict__ wlo,
                short* __restrict__ rhi, short* __restrict__ rmid, short* __restrict__ rlo) {
    int i = blockIdx.x * 256 + threadIdx.x;
    if (i < 294912) {                 // 256 oc * 128 ic * 9 taps
        int n = i / 1152, rem = i % 1152;
        int ic = rem / 9, tap = rem % 9;
        float wv = w1[i];
        unsigned short h = f2bf(wv);
        float r1 = wv - bf2f(h);
        unsigned short m = f2bf(r1);
        float r2 = r1 - bf2f(m);
        unsigned short lo = f2bf(r2);
        int kb = ic >> 5, q = (ic >> 3) & 3, j = ic & 7;
        size_t f = ((((size_t)(kb * 9 + tap)) * 4 + q) * 256 + n) * 8 + j;
        whi[f] = (short)h; wmid[f] = (short)m; wlo[f] = (short)lo;
    }
    if (i < 32768) {                  // 256 oc * 128 ic
        int n = i >> 7, ic = i & 127;
        float wv = wres[i];
        unsigned short h = f2bf(wv);
        float r1 = wv - bf2f(h);
        unsigned short m = f2bf(r1);
        float r2 = r1 - bf2f(m);
        unsigned short lo = f2bf(r2);
        int kb = ic >> 5, q = (ic >> 3) & 3, j = ic & 7;
        size_t f = (((size_t)kb * 4 + q) * 256 + n) * 8 + j;
        rhi[f] = (short)h; rmid[f] = (short)m; rlo[f] = (short)lo;
    }
}

// ---------------------------------------------------------------------------
// k_proj (per t): x_in = x[t] + x_out;  3x3 conv 2->128 + BN + LIF(vp).
// Writes spikes CHANNEL-LAST: s1t[pix_global][ic] u8 (32 bytes/thread, 2x
// uint4 stores).  vp stays planar.
// grid (4 Wtiles, 16 Htiles, B*4 oc-quarters), block 256 = 8 rows x 32 cols
// ---------------------------------------------------------------------------
__global__ __launch_bounds__(256)
void k_proj(const float* __restrict__ xt, const float* __restrict__ xout,
            const float* __restrict__ wp,
            const float* __restrict__ g, const float* __restrict__ bb,
            const float* __restrict__ mm, const float* __restrict__ vv,
            float* __restrict__ vp, unsigned char* __restrict__ s1t) {
    __shared__ float xin[2 * 10 * 36];
    const int tid = threadIdx.x;
    const int b   = blockIdx.z >> 2;
    const int ocq = blockIdx.z & 3;
    const int gy0 = blockIdx.y * 8, gx0 = blockIdx.x * 32;

    for (int i = tid; i < 680; i += 256) {
        int ch = i / 340, rem = i % 340;
        int r = rem / 34, c = rem % 34;
        int gy = gy0 - 1 + r, gx = gx0 - 1 + c;
        float val = 0.f;
        if (gy >= 0 && gy < 128 && gx >= 0 && gx < 128) {
            int idx = ((b * 2 + ch) << 14) + (gy << 7) + gx;
            val = xt[idx] + xout[idx];
        }
        xin[(ch * 10 + r) * 36 + c] = val;
    }
    __syncthreads();

    const int prow = tid >> 5, pcol = tid & 31;
    float xw[2][3][3];
#pragma unroll
    for (int ch = 0; ch < 2; ++ch)
#pragma unroll
        for (int ky = 0; ky < 3; ++ky)
#pragma unroll
            for (int kx = 0; kx < 3; ++kx)
                xw[ch][ky][kx] = xin[(ch * 10 + prow + ky) * 36 + pcol + kx];

    const int pix = ((gy0 + prow) << 7) + gx0 + pcol;
    const int oc_beg = ocq * 32;
    unsigned int pk[8];
#pragma unroll
    for (int k = 0; k < 8; ++k) pk[k] = 0u;
#pragma unroll
    for (int oo = 0; oo < 32; ++oo) {
        const int oc = oc_beg + oo;
        float acc = 0.f;
#pragma unroll
        for (int ch = 0; ch < 2; ++ch)
#pragma unroll
            for (int ky = 0; ky < 3; ++ky)
#pragma unroll
                for (int kx = 0; kx < 3; ++kx)
                    acc = fmaf(wp[((oc * 2 + ch) * 3 + ky) * 3 + kx], xw[ch][ky][kx], acc);
        float sc = g[oc] / sqrtf(vv[oc] + 1e-5f);
        float h  = (acc - mm[oc]) * sc + bb[oc];
        int idx = ((b * 128 + oc) << 14) + pix;
        float v = vp[idx];
        v = v + (h - v) * 0.5f;
        bool s = (v >= 1.0f);
        vp[idx] = s ? 0.f : v;
        pk[oo >> 2] |= (s ? 1u : 0u) << ((oo & 3) * 8);
    }
    unsigned char* dst = s1t + ((((size_t)b << 14) + pix) << 7) + oc_beg;
    *(uint4*)dst        = make_uint4(pk[0], pk[1], pk[2], pk[3]);
    *(uint4*)(dst + 16) = make_uint4(pk[4], pk[5], pk[6], pk[7]);
}

// ---------------------------------------------------------------------------
// k_temp (per t): 3x3 conv 128->2 + BN + LIF(vtm); writes x_out spikes (float).
// Channel-last reads: per window pixel one 8-byte load covers 8 ic; byte->f32
// via cvt.  Weights staged in LDS (uniform broadcast reads).
// grid 256 blocks x 256 thr, one thread per (b,pixel).
// ---------------------------------------------------------------------------
__global__ __launch_bounds__(256)
void k_temp(const unsigned char* __restrict__ s1t, const float* __restrict__ wt,
            const float* __restrict__ g, const float* __restrict__ bb,
            const float* __restrict__ mm, const float* __restrict__ vv,
            float* __restrict__ vtm, float* __restrict__ xout) {
    __shared__ float wls[2304];
    const int tid = threadIdx.x;
    for (int i = tid; i < 2304; i += 256) wls[i] = wt[i];
    __syncthreads();

    const int gid = blockIdx.x * 256 + tid;
    const int b = gid >> 14, pix = gid & 16383;
    const int y = pix >> 7, x = pix & 127;
    const unsigned char* sb = s1t + ((size_t)b << 21);

    float a0 = 0.f, a1 = 0.f;
#pragma unroll
    for (int dy = 0; dy < 3; ++dy) {
        int yy = y - 1 + dy;
#pragma unroll
        for (int dx = 0; dx < 3; ++dx) {
            int xx = x - 1 + dx;
            int tap = dy * 3 + dx;
            if (yy >= 0 && yy < 128 && xx >= 0 && xx < 128) {
                const unsigned char* pp = sb + ((((size_t)(yy << 7)) + xx) << 7);
#pragma unroll
                for (int icb = 0; icb < 16; ++icb) {
                    uint2 d = *(const uint2*)(pp + icb * 8);
#pragma unroll
                    for (int j = 0; j < 4; ++j) {
                        float f0 = (float)((d.x >> (8 * j)) & 0xFFu);
                        float f1 = (float)((d.y >> (8 * j)) & 0xFFu);
                        int ic0 = icb * 8 + j, ic1 = icb * 8 + 4 + j;
                        a0 = fmaf(wls[ic0 * 9 + tap], f0, a0);
                        a0 = fmaf(wls[ic1 * 9 + tap], f1, a0);
                        a1 = fmaf(wls[1152 + ic0 * 9 + tap], f0, a1);
                        a1 = fmaf(wls[1152 + ic1 * 9 + tap], f1, a1);
                    }
                }
            }
        }
    }
#pragma unroll
    for (int oc = 0; oc < 2; ++oc) {
        float acc = (oc == 0) ? a0 : a1;
        float sc = g[oc] / sqrtf(vv[oc] + 1e-5f);
        float yv = (acc - mm[oc]) * sc + bb[oc];
        int idx = ((b * 2 + oc) << 14) + pix;
        float v = vtm[idx];
        v = v + (yv - v) * 0.5f;
        bool s = (v >= 1.0f);
        vtm[idx]  = s ? 0.f : v;
        xout[idx] = s ? 1.0f : 0.f;
    }
}

// ---------------------------------------------------------------------------
// k_fused: [3x3 conv 128->256 + BN + LIF] + [1x1 res conv + BN + LIF] fused,
// t-loop inside (all 4 LIF-state arrays in registers), out = sa + sr written
// ONCE (no RMW).  mfma_f32_16x16x32_bf16, 3-way exact weight split.
// Res conv reuses the ky=1,kx=1 A-fragment (same LDS tile, zero extra reads).
// LDS spike tile: entry(icb,p) at (icb*181+p)*16 B (pad 181 -> <=2-way banks).
// Block 256 = 4 waves (2x2); wave tile 64px x 32oc; block 128px x 64oc.
// grid (4 oc-tiles, 512 px-tiles = b*128 + ry*8 + cx)
// ---------------------------------------------------------------------------
__global__ __launch_bounds__(256, 2)
void k_fused(const unsigned char* __restrict__ s1c,
             const short* __restrict__ whi, const short* __restrict__ wmid,
             const short* __restrict__ wlo,
             const short* __restrict__ rhi, const short* __restrict__ rmid,
             const short* __restrict__ rlo,
             const float* __restrict__ g1, const float* __restrict__ b1,
             const float* __restrict__ m1, const float* __restrict__ v1,
             const float* __restrict__ gr, const float* __restrict__ br,
             const float* __restrict__ mr, const float* __restrict__ vr,
             float* __restrict__ out) {
    __shared__ __align__(16) char lds[46336];   // 16*181 entries * 16B
    float* tr = (float*)lds;                    // reused: 64x132 f32 transpose

    const int tid = threadIdx.x;
    const int oc0 = blockIdx.x * 64;
    const int yb = blockIdx.y;
    const int b = yb >> 7, ry = (yb >> 3) & 15, cx = yb & 7;
    const int gy0 = ry * 8, gx0 = cx * 16;

    const int w  = tid >> 6, l = tid & 63;
    const int q  = l >> 4,  ln = l & 15;
    const int wm = w >> 1,  wn = w & 1;

    float sca[2], mma[2], bba[2], scr[2], mmr[2], bbr[2];
#pragma unroll
    for (int nt = 0; nt < 2; ++nt) {
        int oc = oc0 + wn * 32 + nt * 16 + ln;
        sca[nt] = g1[oc] / sqrtf(v1[oc] + 1e-5f);
        mma[nt] = m1[oc]; bba[nt] = b1[oc];
        scr[nt] = gr[oc] / sqrtf(vr[oc] + 1e-5f);
        mmr[nt] = mr[oc]; bbr[nt] = br[oc];
    }

    const size_t bofs = ((size_t)q * 256 + oc0 + wn * 32 + ln) * 8;
    const int abase = q * 2896 + wm * 1152 + ln * 16;   // bytes into lds

    float va[4][2][4], vres[4][2][4];
#pragma unroll
    for (int i = 0; i < 4; ++i)
#pragma unroll
        for (int nt = 0; nt < 2; ++nt)
#pragma unroll
            for (int rg = 0; rg < 4; ++rg) { va[i][nt][rg] = 0.f; vres[i][nt][rg] = 0.f; }

#pragma unroll 1
    for (int t = 0; t < 4; ++t) {
        const unsigned char* s1t = s1c + (size_t)t * 8388608 + ((size_t)b << 21);

        // ---- stage spike window: entry(icb,p) <- 8 ic bf16; coalesced u8
        // channel-last loads (wave reads 512 contiguous bytes) ----
        for (int cc = tid; cc < 2880; cc += 256) {
            int p = cc >> 4, icb = cc & 15;
            int r = p / 18, c = p - r * 18;
            int gy = gy0 - 1 + r, gx = gx0 - 1 + c;
            uint2 d = make_uint2(0u, 0u);
            if (gy >= 0 && gy < 128 && gx >= 0 && gx < 128)
                d = *(const uint2*)(s1t + ((size_t)((gy << 7) + gx) << 7) + icb * 8);
            uint4 pk;
            pk.x = ((d.x & 1u)          | ((d.x & 0x100u) << 8))   * 0x3F80u;
            pk.y = (((d.x >> 16) & 1u)  | ((d.x >> 8) & 0x10000u)) * 0x3F80u;
            pk.z = ((d.y & 1u)          | ((d.y & 0x100u) << 8))   * 0x3F80u;
            pk.w = (((d.y >> 16) & 1u)  | ((d.y >> 8) & 0x10000u)) * 0x3F80u;
            *(uint4*)(lds + (icb * 181 + p) * 16) = pk;
        }
        __syncthreads();

        f32x4 acc[4][2], accr[4][2];
#pragma unroll
        for (int i = 0; i < 4; ++i)
#pragma unroll
            for (int nt = 0; nt < 2; ++nt) { acc[i][nt] = (f32x4)(0.f); accr[i][nt] = (f32x4)(0.f); }

        const short* bh = whi  + bofs;
        const short* bm = wmid + bofs;
        const short* bl = wlo  + bofs;
        const short* ch = rhi  + bofs;
        const short* cm = rmid + bofs;
        const short* cl = rlo  + bofs;
        int ab = abase;

#pragma unroll 1
        for (int kb = 0; kb < 4; ++kb) {
#pragma unroll
            for (int ky = 0; ky < 3; ++ky) {
#pragma unroll
                for (int kx = 0; kx < 3; ++kx) {
                    short8 A[4];
#pragma unroll
                    for (int i = 0; i < 4; ++i)
                        A[i] = *(const short8*)(lds + ab + (i + ky) * 288 + kx * 16);
                    short8 BH[2], BM[2], BL[2];
#pragma unroll
                    for (int nt = 0; nt < 2; ++nt) {
                        BH[nt] = *(const short8*)(bh + nt * 128);
                        BM[nt] = *(const short8*)(bm + nt * 128);
                        BL[nt] = *(const short8*)(bl + nt * 128);
                    }
#pragma unroll
                    for (int i = 0; i < 4; ++i)
#pragma unroll
                        for (int nt = 0; nt < 2; ++nt) {
                            acc[i][nt] = __builtin_amdgcn_mfma_f32_16x16x32_bf16(A[i], BH[nt], acc[i][nt], 0, 0, 0);
                            acc[i][nt] = __builtin_amdgcn_mfma_f32_16x16x32_bf16(A[i], BM[nt], acc[i][nt], 0, 0, 0);
                            acc[i][nt] = __builtin_amdgcn_mfma_f32_16x16x32_bf16(A[i], BL[nt], acc[i][nt], 0, 0, 0);
                        }
                    if (ky == 1 && kx == 1) {   // res conv: same A (center tap)
                        short8 CH[2], CM[2], CL[2];
#pragma unroll
                        for (int nt = 0; nt < 2; ++nt) {
                            CH[nt] = *(const short8*)(ch + nt * 128);
                            CM[nt] = *(const short8*)(cm + nt * 128);
                            CL[nt] = *(const short8*)(cl + nt * 128);
                        }
#pragma unroll
                        for (int i = 0; i < 4; ++i)
#pragma unroll
                            for (int nt = 0; nt < 2; ++nt) {
                                accr[i][nt] = __builtin_amdgcn_mfma_f32_16x16x32_bf16(A[i], CH[nt], accr[i][nt], 0, 0, 0);
                                accr[i][nt] = __builtin_amdgcn_mfma_f32_16x16x32_bf16(A[i], CM[nt], accr[i][nt], 0, 0, 0);
                                accr[i][nt] = __builtin_amdgcn_mfma_f32_16x16x32_bf16(A[i], CL[nt], accr[i][nt], 0, 0, 0);
                            }
                    }
                    bh += 8192; bm += 8192; bl += 8192;
                }
            }
            ch += 8192; cm += 8192; cl += 8192;
            ab += 11584;
        }
        __syncthreads();   // done reading s-tile; lds becomes transpose buffer

        // ---- BN + LIF (both paths) + transpose sum into [oc 64][px 132] ----
#pragma unroll
        for (int i = 0; i < 4; ++i)
#pragma unroll
            for (int nt = 0; nt < 2; ++nt) {
                float ofs[4];
#pragma unroll
                for (int rg = 0; rg < 4; ++rg) {
                    float ha = (acc[i][nt][rg] - mma[nt]) * sca[nt] + bba[nt];
                    float v = va[i][nt][rg];
                    v = v + (ha - v) * 0.5f;
                    bool s = (v >= 1.0f);
                    va[i][nt][rg] = s ? 0.f : v;
                    float sa = s ? 1.f : 0.f;

                    float hr = (accr[i][nt][rg] - mmr[nt]) * scr[nt] + bbr[nt];
                    float u = vres[i][nt][rg];
                    u = u + (hr - u) * 0.5f;
                    bool sr = (u >= 1.0f);
                    vres[i][nt][rg] = sr ? 0.f : u;

                    ofs[rg] = sa + (sr ? 1.f : 0.f);
                }
                float* dst = &tr[(wn * 32 + nt * 16 + ln) * 132 + (wm * 4 + i) * 16 + q * 4];
                dst[0] = ofs[0]; dst[1] = ofs[1]; dst[2] = ofs[2]; dst[3] = ofs[3];
            }
        __syncthreads();

        // ---- coalesced store (single write, no RMW) ----
        const size_t obase = ((size_t)((t * 4 + b) * 256 + oc0)) << 14;
#pragma unroll
        for (int rr = 0; rr < 16; ++rr) {
            int ocr = w * 16 + rr;
#pragma unroll
            for (int hf = 0; hf < 2; ++hf) {
                int px = hf * 64 + l;
                out[obase + ((size_t)ocr << 14) + ((gy0 + (px >> 4)) << 7) + gx0 + (px & 15)]
                    = tr[ocr * 132 + px];
            }
        }
        __syncthreads();   // before next t's staging
    }
}

// ---------------------------------------------------------------------------
// Workspace layout (bytes):
//   s1c   @ 0          33,554,432  (u8 spikes CHANNEL-LAST [T][B][pix][128ic])
//   vp    @ 33,554,432 33,554,432  (float LIF state; DEAD after t-loop ->
//     weight planes overlap it:  whi @33,554,432 (589,824), wmid, wlo,
//     rhi @35,323,904 (65,536), rmid, rlo  — end 35,520,512)
//   vtm   @ 67,108,864    524,288
//   xout  @ 67,633,152    524,288     total = 68,157,440
// ---------------------------------------------------------------------------
extern "C" void kernel_launch(void* const* d_in, const int* in_sizes, int n_in,
                              void* d_out, int out_size, void* d_ws, size_t ws_size,
                              hipStream_t stream) {
    const float* x      = (const float*)d_in[0];
    const float* w_proj = (const float*)d_in[1];
    const float* g0 = (const float*)d_in[2];
    const float* b0 = (const float*)d_in[3];
    const float* m0 = (const float*)d_in[4];
    const float* v0 = (const float*)d_in[5];
    const float* w_temp = (const float*)d_in[6];
    const float* gt = (const float*)d_in[7];
    const float* bt = (const float*)d_in[8];
    const float* mt = (const float*)d_in[9];
    const float* vt = (const float*)d_in[10];
    const float* w1 = (const float*)d_in[11];
    const float* g1 = (const float*)d_in[12];
    const float* b1 = (const float*)d_in[13];
    const float* m1 = (const float*)d_in[14];
    const float* v1 = (const float*)d_in[15];
    const float* w_res = (const float*)d_in[16];
    const float* gr = (const float*)d_in[17];
    const float* br = (const float*)d_in[18];
    const float* mr = (const float*)d_in[19];
    const float* vr = (const float*)d_in[20];

    char* ws = (char*)d_ws;
    unsigned char* s1c = (unsigned char*)ws;
    float* vp   = (float*)(ws + 33554432);
    short* whi  = (short*)(ws + 33554432);   // overlaps vp (dead after t-loop)
    short* wmid = (short*)(ws + 34144256);
    short* wlo  = (short*)(ws + 34734080);
    short* rhi  = (short*)(ws + 35323904);
    short* rmid = (short*)(ws + 35389440);
    short* rlo  = (short*)(ws + 35454976);
    float* vtm  = (float*)(ws + 67108864);
    float* xout = (float*)(ws + 67633152);

    // zero LIF states + recurrent x_out
    hipMemsetAsync(ws + 33554432, 0, 34603008, stream);

    for (int t = 0; t < 4; ++t) {
        const float* xt = x + (size_t)t * 4 * 2 * HW;
        unsigned char* s1t = s1c + (size_t)t * 8388608;
        k_proj<<<dim3(4, 16, 16), dim3(256), 0, stream>>>(
            xt, xout, w_proj, g0, b0, m0, v0, vp, s1t);
        k_temp<<<dim3(256), dim3(256), 0, stream>>>(
            s1t, w_temp, gt, bt, mt, vt, vtm, xout);
    }

    // weights reorder AFTER the t-loop (vp is dead, planes overlap it)
    k_reorder3<<<dim3(1152), dim3(256), 0, stream>>>(
        w1, w_res, whi, wmid, wlo, rhi, rmid, rlo);

    k_fused<<<dim3(4, 512), dim3(256), 0, stream>>>(
        s1c, whi, wmid, wlo, rhi, rmid, rlo,
        g1, b1, m1, v1, gr, br, mr, vr, (float*)d_out);
}

// Round 5
// 1223.295 us; speedup vs baseline: 4.3213x; 1.0448x over previous
//
#include <hip/hip_runtime.h>
#include <math.h>

// Problem constants: T=4, B=4, C=2, H=W=128 (HW=16384), E=256, half=128.
#define HW 16384

typedef __attribute__((ext_vector_type(8))) short short8;
typedef __attribute__((ext_vector_type(4))) float f32x4;

__device__ inline unsigned short f2bf(float f) {
    unsigned int u = __float_as_uint(f);
    u += 0x7FFF + ((u >> 16) & 1);          // RNE
    return (unsigned short)(u >> 16);
}
__device__ inline float bf2f(unsigned short h) {
    return __uint_as_float(((unsigned int)h) << 16);
}

// ---------------------------------------------------------------------------
// k_reorder3: 3-way EXACT bf16 split of w1 and w_res into MFMA-B layout:
// w1 -> plane[kb 4][tap 9][quad 4][n 256][j 8], ic = kb*32+quad*8+j.
// w_res -> plane[kb 4][quad 4][n 256][j 8].  hi+mid+lo == w bit-exactly.
// ---------------------------------------------------------------------------
__global__ __launch_bounds__(256)
void k_reorder3(const float* __restrict__ w1, const float* __restrict__ wres,
                short* __restrict__ whi, short* __restrict__ wmid, short* __restrict__ wlo,
                short* __restrict__ rhi, short* __restrict__ rmid, short* __restrict__ rlo) {
    int i = blockIdx.x * 256 + threadIdx.x;
    if (i < 294912) {                 // 256 oc * 128 ic * 9 taps
        int n = i / 1152, rem = i % 1152;
        int ic = rem / 9, tap = rem % 9;
        float wv = w1[i];
        unsigned short h = f2bf(wv);
        float r1 = wv - bf2f(h);
        unsigned short m = f2bf(r1);
        float r2 = r1 - bf2f(m);
        unsigned short lo = f2bf(r2);
        int kb = ic >> 5, q = (ic >> 3) & 3, j = ic & 7;
        size_t f = ((((size_t)(kb * 9 + tap)) * 4 + q) * 256 + n) * 8 + j;
        whi[f] = (short)h; wmid[f] = (short)m; wlo[f] = (short)lo;
    }
    if (i < 32768) {                  // 256 oc * 128 ic
        int n = i >> 7, ic = i & 127;
        float wv = wres[i];
        unsigned short h = f2bf(wv);
        float r1 = wv - bf2f(h);
        unsigned short m = f2bf(r1);
        float r2 = r1 - bf2f(m);
        unsigned short lo = f2bf(r2);
        int kb = ic >> 5, q = (ic >> 3) & 3, j = ic & 7;
        size_t f = (((size_t)kb * 4 + q) * 256 + n) * 8 + j;
        rhi[f] = (short)h; rmid[f] = (short)m; rlo[f] = (short)lo;
    }
}

// ---------------------------------------------------------------------------
// k_proj (per t): x_in = x[t] + x_out;  3x3 conv 2->128 + BN + LIF(vp).
// Writes spikes CHANNEL-LAST: s1t[b][pix][ic] u8 (32 B/thread, 2x uint4).
// grid (4 Wtiles, 16 Htiles, B*4 oc-quarters), block 256 = 8 rows x 32 cols
// ---------------------------------------------------------------------------
__global__ __launch_bounds__(256)
void k_proj(const float* __restrict__ xt, const float* __restrict__ xout,
            const float* __restrict__ wp,
            const float* __restrict__ g, const float* __restrict__ bb,
            const float* __restrict__ mm, const float* __restrict__ vv,
            float* __restrict__ vp, unsigned char* __restrict__ s1t) {
    __shared__ float xin[2 * 10 * 36];
    const int tid = threadIdx.x;
    const int b   = blockIdx.z >> 2;
    const int ocq = blockIdx.z & 3;
    const int gy0 = blockIdx.y * 8, gx0 = blockIdx.x * 32;

    for (int i = tid; i < 680; i += 256) {
        int ch = i / 340, rem = i % 340;
        int r = rem / 34, c = rem % 34;
        int gy = gy0 - 1 + r, gx = gx0 - 1 + c;
        float val = 0.f;
        if (gy >= 0 && gy < 128 && gx >= 0 && gx < 128) {
            int idx = ((b * 2 + ch) << 14) + (gy << 7) + gx;
            val = xt[idx] + xout[idx];
        }
        xin[(ch * 10 + r) * 36 + c] = val;
    }
    __syncthreads();

    const int prow = tid >> 5, pcol = tid & 31;
    float xw[2][3][3];
#pragma unroll
    for (int ch = 0; ch < 2; ++ch)
#pragma unroll
        for (int ky = 0; ky < 3; ++ky)
#pragma unroll
            for (int kx = 0; kx < 3; ++kx)
                xw[ch][ky][kx] = xin[(ch * 10 + prow + ky) * 36 + pcol + kx];

    const int pix = ((gy0 + prow) << 7) + gx0 + pcol;
    const int oc_beg = ocq * 32;
    unsigned int pk[8];
#pragma unroll
    for (int k = 0; k < 8; ++k) pk[k] = 0u;
#pragma unroll
    for (int oo = 0; oo < 32; ++oo) {
        const int oc = oc_beg + oo;
        float acc = 0.f;
#pragma unroll
        for (int ch = 0; ch < 2; ++ch)
#pragma unroll
            for (int ky = 0; ky < 3; ++ky)
#pragma unroll
                for (int kx = 0; kx < 3; ++kx)
                    acc = fmaf(wp[((oc * 2 + ch) * 3 + ky) * 3 + kx], xw[ch][ky][kx], acc);
        float sc = g[oc] / sqrtf(vv[oc] + 1e-5f);
        float h  = (acc - mm[oc]) * sc + bb[oc];
        int idx = ((b * 128 + oc) << 14) + pix;
        float v = vp[idx];
        v = v + (h - v) * 0.5f;
        bool s = (v >= 1.0f);
        vp[idx] = s ? 0.f : v;
        pk[oo >> 2] |= (s ? 1u : 0u) << ((oo & 3) * 8);
    }
    unsigned char* dst = s1t + ((((size_t)b << 14) + pix) << 7) + oc_beg;
    *(uint4*)dst        = make_uint4(pk[0], pk[1], pk[2], pk[3]);
    *(uint4*)(dst + 16) = make_uint4(pk[4], pk[5], pk[6], pk[7]);
}

// ---------------------------------------------------------------------------
// k_temp (per t): 3x3 conv 128->2 + BN + LIF(vtm); writes x_out spikes (float).
// 1-row tiles: stage the 3-row x 128-px x 128-ic u8 window (48 KB) in LDS
// with coalesced uint4 global loads; 8B XOR swizzle p^(icb&7) keeps both
// LDS write and read sides <=2-way bank aliasing (free).
// grid (128 rows, B), block 128 (one thread per out pixel).
// ---------------------------------------------------------------------------
__global__ __launch_bounds__(128)
void k_temp(const unsigned char* __restrict__ s1t, const float* __restrict__ wt,
            const float* __restrict__ g, const float* __restrict__ bb,
            const float* __restrict__ mm, const float* __restrict__ vv,
            float* __restrict__ vtm, float* __restrict__ xout) {
    __shared__ unsigned char sl[49152];   // [icb 16][r 3][p 128] * 8B
    __shared__ float wls[2304];
    const int tid = threadIdx.x;
    const int b   = blockIdx.y;
    const int y0  = blockIdx.x;

    for (int i = tid; i < 2304; i += 128) wls[i] = wt[i];

    const unsigned char* sb = s1t + ((size_t)b << 21);
#pragma unroll
    for (int r = 0; r < 3; ++r) {
        int gy = y0 - 1 + r;
        bool ok = (gy >= 0 && gy < 128);
        const unsigned char* rowp = sb + ((size_t)gy << 14);
#pragma unroll
        for (int k = 0; k < 8; ++k) {
            int c = tid + k * 128;              // chunk in [0,1024), 16 B each
            uint4 d = make_uint4(0u, 0u, 0u, 0u);
            if (ok) d = *(const uint4*)(rowp + c * 16);
            int p = c >> 3;
            int icb0 = (c & 7) * 2;
            int p0 = p ^ (icb0 & 7);
            int p1 = p ^ ((icb0 + 1) & 7);
            *(uint2*)&sl[(((icb0)     * 3 + r) * 128 + p0) * 8] = make_uint2(d.x, d.y);
            *(uint2*)&sl[(((icb0 + 1) * 3 + r) * 128 + p1) * 8] = make_uint2(d.z, d.w);
        }
    }
    __syncthreads();

    const int x = tid;
    float a0 = 0.f, a1 = 0.f;
#pragma unroll 1
    for (int icb = 0; icb < 16; ++icb) {
        int sw = icb & 7;
        const float* w0 = &wls[icb * 72];
        const float* w1 = &wls[1152 + icb * 72];
#pragma unroll
        for (int dy = 0; dy < 3; ++dy) {
#pragma unroll
            for (int dx = 0; dx < 3; ++dx) {
                int xx = x - 1 + dx;
                if (xx < 0 || xx > 127) continue;
                uint2 d = *(const uint2*)&sl[((icb * 3 + dy) * 128 + (xx ^ sw)) * 8];
                int tap = dy * 3 + dx;
#pragma unroll
                for (int j = 0; j < 4; ++j) {
                    float f0 = (float)((d.x >> (8 * j)) & 0xFFu);
                    float f1 = (float)((d.y >> (8 * j)) & 0xFFu);
                    a0 = fmaf(w0[j * 9 + tap],        f0, a0);
                    a0 = fmaf(w0[(4 + j) * 9 + tap],  f1, a0);
                    a1 = fmaf(w1[j * 9 + tap],        f0, a1);
                    a1 = fmaf(w1[(4 + j) * 9 + tap],  f1, a1);
                }
            }
        }
    }
#pragma unroll
    for (int oc = 0; oc < 2; ++oc) {
        float acc = (oc == 0) ? a0 : a1;
        float sc = g[oc] / sqrtf(vv[oc] + 1e-5f);
        float yv = (acc - mm[oc]) * sc + bb[oc];
        int idx = ((b * 2 + oc) << 14) + (y0 << 7) + x;
        float v = vtm[idx];
        v = v + (yv - v) * 0.5f;
        bool s = (v >= 1.0f);
        vtm[idx]  = s ? 0.f : v;
        xout[idx] = s ? 1.0f : 0.f;
    }
}

// ---------------------------------------------------------------------------
// k_fused: [3x3 conv 128->256 + BN + LIF] + [1x1 res conv + BN + LIF] fused,
// t-loop inside (all 4 LIF-state arrays in registers), out = sa + sr once.
// mfma_f32_16x16x32_bf16, 3-way exact weight split; res conv reuses the
// center-tap A fragment.  LDS tile: entry(icb,p) at (icb*181+p)*16 B.
// Transpose buffer row stride 140 floats (12*ln%32 -> ~2-way banks, was ~8).
// launch_bounds(256,3): 3 blocks/CU (LDS 46.6KB*3=139.8 <=160; VGPR<=170).
// grid (4 oc-tiles, 512 px-tiles = b*128 + ry*8 + cx)
// ---------------------------------------------------------------------------
__global__ __launch_bounds__(256, 3)
void k_fused(const unsigned char* __restrict__ s1c,
             const short* __restrict__ whi, const short* __restrict__ wmid,
             const short* __restrict__ wlo,
             const short* __restrict__ rhi, const short* __restrict__ rmid,
             const short* __restrict__ rlo,
             const float* __restrict__ g1, const float* __restrict__ b1,
             const float* __restrict__ m1, const float* __restrict__ v1,
             const float* __restrict__ gr, const float* __restrict__ br,
             const float* __restrict__ mr, const float* __restrict__ vr,
             float* __restrict__ out) {
    __shared__ __align__(16) char lds[46336];   // 16*181 entries * 16B
    float* tr = (float*)lds;                    // reused: 64 x 140 f32 transpose

    const int tid = threadIdx.x;
    const int oc0 = blockIdx.x * 64;
    const int yb = blockIdx.y;
    const int b = yb >> 7, ry = (yb >> 3) & 15, cx = yb & 7;
    const int gy0 = ry * 8, gx0 = cx * 16;

    const int w  = tid >> 6, l = tid & 63;
    const int q  = l >> 4,  ln = l & 15;
    const int wm = w >> 1,  wn = w & 1;

    float sca[2], mma[2], bba[2], scr[2], mmr[2], bbr[2];
#pragma unroll
    for (int nt = 0; nt < 2; ++nt) {
        int oc = oc0 + wn * 32 + nt * 16 + ln;
        sca[nt] = g1[oc] / sqrtf(v1[oc] + 1e-5f);
        mma[nt] = m1[oc]; bba[nt] = b1[oc];
        scr[nt] = gr[oc] / sqrtf(vr[oc] + 1e-5f);
        mmr[nt] = mr[oc]; bbr[nt] = br[oc];
    }

    const size_t bofs = ((size_t)q * 256 + oc0 + wn * 32 + ln) * 8;
    const int abase = q * 2896 + wm * 1152 + ln * 16;   // bytes into lds

    float va[4][2][4], vres[4][2][4];
#pragma unroll
    for (int i = 0; i < 4; ++i)
#pragma unroll
        for (int nt = 0; nt < 2; ++nt)
#pragma unroll
            for (int rg = 0; rg < 4; ++rg) { va[i][nt][rg] = 0.f; vres[i][nt][rg] = 0.f; }

#pragma unroll 1
    for (int t = 0; t < 4; ++t) {
        const unsigned char* s1t = s1c + (size_t)t * 8388608 + ((size_t)b << 21);

        // ---- stage spike window: entry(icb,p) <- 8 ic bf16; coalesced u8
        // channel-last loads (wave reads 512 contiguous bytes) ----
        for (int cc = tid; cc < 2880; cc += 256) {
            int p = cc >> 4, icb = cc & 15;
            int r = p / 18, c = p - r * 18;
            int gy = gy0 - 1 + r, gx = gx0 - 1 + c;
            uint2 d = make_uint2(0u, 0u);
            if (gy >= 0 && gy < 128 && gx >= 0 && gx < 128)
                d = *(const uint2*)(s1t + ((size_t)((gy << 7) + gx) << 7) + icb * 8);
            uint4 pk;
            pk.x = ((d.x & 1u)          | ((d.x & 0x100u) << 8))   * 0x3F80u;
            pk.y = (((d.x >> 16) & 1u)  | ((d.x >> 8) & 0x10000u)) * 0x3F80u;
            pk.z = ((d.y & 1u)          | ((d.y & 0x100u) << 8))   * 0x3F80u;
            pk.w = (((d.y >> 16) & 1u)  | ((d.y >> 8) & 0x10000u)) * 0x3F80u;
            *(uint4*)(lds + (icb * 181 + p) * 16) = pk;
        }
        __syncthreads();

        f32x4 acc[4][2], accr[4][2];
#pragma unroll
        for (int i = 0; i < 4; ++i)
#pragma unroll
            for (int nt = 0; nt < 2; ++nt) { acc[i][nt] = (f32x4)(0.f); accr[i][nt] = (f32x4)(0.f); }

        const short* bh = whi  + bofs;
        const short* bm = wmid + bofs;
        const short* bl = wlo  + bofs;
        const short* ch = rhi  + bofs;
        const short* cm = rmid + bofs;
        const short* cl = rlo  + bofs;
        int ab = abase;

#pragma unroll 1
        for (int kb = 0; kb < 4; ++kb) {
#pragma unroll
            for (int ky = 0; ky < 3; ++ky) {
#pragma unroll
                for (int kx = 0; kx < 3; ++kx) {
                    short8 A[4];
#pragma unroll
                    for (int i = 0; i < 4; ++i)
                        A[i] = *(const short8*)(lds + ab + (i + ky) * 288 + kx * 16);
                    short8 BH[2], BM[2], BL[2];
#pragma unroll
                    for (int nt = 0; nt < 2; ++nt) {
                        BH[nt] = *(const short8*)(bh + nt * 128);
                        BM[nt] = *(const short8*)(bm + nt * 128);
                        BL[nt] = *(const short8*)(bl + nt * 128);
                    }
#pragma unroll
                    for (int i = 0; i < 4; ++i)
#pragma unroll
                        for (int nt = 0; nt < 2; ++nt) {
                            acc[i][nt] = __builtin_amdgcn_mfma_f32_16x16x32_bf16(A[i], BH[nt], acc[i][nt], 0, 0, 0);
                            acc[i][nt] = __builtin_amdgcn_mfma_f32_16x16x32_bf16(A[i], BM[nt], acc[i][nt], 0, 0, 0);
                            acc[i][nt] = __builtin_amdgcn_mfma_f32_16x16x32_bf16(A[i], BL[nt], acc[i][nt], 0, 0, 0);
                        }
                    if (ky == 1 && kx == 1) {   // res conv: same A (center tap)
                        short8 CH[2], CM[2], CL[2];
#pragma unroll
                        for (int nt = 0; nt < 2; ++nt) {
                            CH[nt] = *(const short8*)(ch + nt * 128);
                            CM[nt] = *(const short8*)(cm + nt * 128);
                            CL[nt] = *(const short8*)(cl + nt * 128);
                        }
#pragma unroll
                        for (int i = 0; i < 4; ++i)
#pragma unroll
                            for (int nt = 0; nt < 2; ++nt) {
                                accr[i][nt] = __builtin_amdgcn_mfma_f32_16x16x32_bf16(A[i], CH[nt], accr[i][nt], 0, 0, 0);
                                accr[i][nt] = __builtin_amdgcn_mfma_f32_16x16x32_bf16(A[i], CM[nt], accr[i][nt], 0, 0, 0);
                                accr[i][nt] = __builtin_amdgcn_mfma_f32_16x16x32_bf16(A[i], CL[nt], accr[i][nt], 0, 0, 0);
                            }
                    }
                    bh += 8192; bm += 8192; bl += 8192;
                }
            }
            ch += 8192; cm += 8192; cl += 8192;
            ab += 11584;
        }
        __syncthreads();   // done reading s-tile; lds becomes transpose buffer

        // ---- BN + LIF (both paths) + transpose sum into [oc 64][px, stride 140] ----
#pragma unroll
        for (int i = 0; i < 4; ++i)
#pragma unroll
            for (int nt = 0; nt < 2; ++nt) {
                float ofs[4];
#pragma unroll
                for (int rg = 0; rg < 4; ++rg) {
                    float ha = (acc[i][nt][rg] - mma[nt]) * sca[nt] + bba[nt];
                    float v = va[i][nt][rg];
                    v = v + (ha - v) * 0.5f;
                    bool s = (v >= 1.0f);
                    va[i][nt][rg] = s ? 0.f : v;
                    float sa = s ? 1.f : 0.f;

                    float hr = (accr[i][nt][rg] - mmr[nt]) * scr[nt] + bbr[nt];
                    float u = vres[i][nt][rg];
                    u = u + (hr - u) * 0.5f;
                    bool sr = (u >= 1.0f);
                    vres[i][nt][rg] = sr ? 0.f : u;

                    ofs[rg] = sa + (sr ? 1.f : 0.f);
                }
                float* dst = &tr[(wn * 32 + nt * 16 + ln) * 140 + (wm * 4 + i) * 16 + q * 4];
                dst[0] = ofs[0]; dst[1] = ofs[1]; dst[2] = ofs[2]; dst[3] = ofs[3];
            }
        __syncthreads();

        // ---- coalesced store (single write, no RMW) ----
        const size_t obase = ((size_t)((t * 4 + b) * 256 + oc0)) << 14;
#pragma unroll
        for (int rr = 0; rr < 16; ++rr) {
            int ocr = w * 16 + rr;
#pragma unroll
            for (int hf = 0; hf < 2; ++hf) {
                int px = hf * 64 + l;
                out[obase + ((size_t)ocr << 14) + ((gy0 + (px >> 4)) << 7) + gx0 + (px & 15)]
                    = tr[ocr * 140 + px];
            }
        }
        __syncthreads();   // before next t's staging
    }
}

// ---------------------------------------------------------------------------
// Workspace layout (bytes):
//   s1c   @ 0          33,554,432  (u8 spikes CHANNEL-LAST [T][B][pix][128ic])
//   vp    @ 33,554,432 33,554,432  (float LIF state; DEAD after t-loop ->
//     weight planes overlap it:  whi @33,554,432 (589,824), wmid, wlo,
//     rhi @35,323,904 (65,536), rmid, rlo  — end 35,520,512)
//   vtm   @ 67,108,864    524,288
//   xout  @ 67,633,152    524,288     total = 68,157,440
// ---------------------------------------------------------------------------
extern "C" void kernel_launch(void* const* d_in, const int* in_sizes, int n_in,
                              void* d_out, int out_size, void* d_ws, size_t ws_size,
                              hipStream_t stream) {
    const float* x      = (const float*)d_in[0];
    const float* w_proj = (const float*)d_in[1];
    const float* g0 = (const float*)d_in[2];
    const float* b0 = (const float*)d_in[3];
    const float* m0 = (const float*)d_in[4];
    const float* v0 = (const float*)d_in[5];
    const float* w_temp = (const float*)d_in[6];
    const float* gt = (const float*)d_in[7];
    const float* bt = (const float*)d_in[8];
    const float* mt = (const float*)d_in[9];
    const float* vt = (const float*)d_in[10];
    const float* w1 = (const float*)d_in[11];
    const float* g1 = (const float*)d_in[12];
    const float* b1 = (const float*)d_in[13];
    const float* m1 = (const float*)d_in[14];
    const float* v1 = (const float*)d_in[15];
    const float* w_res = (const float*)d_in[16];
    const float* gr = (const float*)d_in[17];
    const float* br = (const float*)d_in[18];
    const float* mr = (const float*)d_in[19];
    const float* vr = (const float*)d_in[20];

    char* ws = (char*)d_ws;
    unsigned char* s1c = (unsigned char*)ws;
    float* vp   = (float*)(ws + 33554432);
    short* whi  = (short*)(ws + 33554432);   // overlaps vp (dead after t-loop)
    short* wmid = (short*)(ws + 34144256);
    short* wlo  = (short*)(ws + 34734080);
    short* rhi  = (short*)(ws + 35323904);
    short* rmid = (short*)(ws + 35389440);
    short* rlo  = (short*)(ws + 35454976);
    float* vtm  = (float*)(ws + 67108864);
    float* xout = (float*)(ws + 67633152);

    // zero LIF states + recurrent x_out
    hipMemsetAsync(ws + 33554432, 0, 34603008, stream);

    for (int t = 0; t < 4; ++t) {
        const float* xt = x + (size_t)t * 4 * 2 * HW;
        unsigned char* s1t = s1c + (size_t)t * 8388608;
        k_proj<<<dim3(4, 16, 16), dim3(256), 0, stream>>>(
            xt, xout, w_proj, g0, b0, m0, v0, vp, s1t);
        k_temp<<<dim3(128, 4), dim3(128), 0, stream>>>(
            s1t, w_temp, gt, bt, mt, vt, vtm, xout);
    }

    // weights reorder AFTER the t-loop (vp is dead, planes overlap it)
    k_reorder3<<<dim3(1152), dim3(256), 0, stream>>>(
        w1, w_res, whi, wmid, wlo, rhi, rmid, rlo);

    k_fused<<<dim3(4, 512), dim3(256), 0, stream>>>(
        s1c, whi, wmid, wlo, rhi, rmid, rlo,
        g1, b1, m1, v1, gr, br, mr, vr, (float*)d_out);
}

// Round 6
// 1133.242 us; speedup vs baseline: 4.6646x; 1.0795x over previous
//
#include <hip/hip_runtime.h>
#include <math.h>

// Problem constants: T=4, B=4, C=2, H=W=128 (HW=16384), E=256, half=128.
#define HW 16384

typedef __attribute__((ext_vector_type(8))) short short8;
typedef __attribute__((ext_vector_type(4))) float f32x4;

__device__ inline unsigned short f2bf(float f) {
    unsigned int u = __float_as_uint(f);
    u += 0x7FFF + ((u >> 16) & 1);          // RNE
    return (unsigned short)(u >> 16);
}
__device__ inline float bf2f(unsigned short h) {
    return __uint_as_float(((unsigned int)h) << 16);
}

// ---------------------------------------------------------------------------
// k_reorder3: BN-FOLDED 3-way EXACT bf16 split of w1*sc1 and w_res*scr into
// MFMA-A layout: plane[kb 4][tap 9][quad 4][oc 256][j 8], ic = kb*32+q*8+j.
// hi+mid+lo == (w*sc rounded to fp32) bit-exactly.  Also emits the folded
// biases b - m*sc (acc init), so the epilogue needs no BN constants.
// ---------------------------------------------------------------------------
__global__ __launch_bounds__(256)
void k_reorder3(const float* __restrict__ w1, const float* __restrict__ wres,
                const float* __restrict__ g1, const float* __restrict__ b1,
                const float* __restrict__ m1, const float* __restrict__ v1,
                const float* __restrict__ gr, const float* __restrict__ br,
                const float* __restrict__ mr, const float* __restrict__ vr,
                short* __restrict__ whi, short* __restrict__ wmid, short* __restrict__ wlo,
                short* __restrict__ rhi, short* __restrict__ rmid, short* __restrict__ rlo,
                float* __restrict__ bias1, float* __restrict__ biasr) {
    int i = blockIdx.x * 256 + threadIdx.x;
    if (i < 294912) {                 // 256 oc * 128 ic * 9 taps
        int n = i / 1152, rem = i % 1152;
        int ic = rem / 9, tap = rem % 9;
        float sc = g1[n] / sqrtf(v1[n] + 1e-5f);
        float wv = w1[i] * sc;
        unsigned short h = f2bf(wv);
        float r1 = wv - bf2f(h);
        unsigned short m = f2bf(r1);
        float r2 = r1 - bf2f(m);
        unsigned short lo = f2bf(r2);
        int kb = ic >> 5, q = (ic >> 3) & 3, j = ic & 7;
        size_t f = ((((size_t)(kb * 9 + tap)) * 4 + q) * 256 + n) * 8 + j;
        whi[f] = (short)h; wmid[f] = (short)m; wlo[f] = (short)lo;
    }
    if (i < 32768) {                  // 256 oc * 128 ic
        int n = i >> 7, ic = i & 127;
        float sc = gr[n] / sqrtf(vr[n] + 1e-5f);
        float wv = wres[i] * sc;
        unsigned short h = f2bf(wv);
        float r1 = wv - bf2f(h);
        unsigned short m = f2bf(r1);
        float r2 = r1 - bf2f(m);
        unsigned short lo = f2bf(r2);
        int kb = ic >> 5, q = (ic >> 3) & 3, j = ic & 7;
        size_t f = (((size_t)kb * 4 + q) * 256 + n) * 8 + j;
        rhi[f] = (short)h; rmid[f] = (short)m; rlo[f] = (short)lo;
    }
    if (i < 256) {
        float sc1 = g1[i] / sqrtf(v1[i] + 1e-5f);
        bias1[i] = b1[i] - m1[i] * sc1;
        float scr_ = gr[i] / sqrtf(vr[i] + 1e-5f);
        biasr[i] = br[i] - mr[i] * scr_;
    }
}

// ---------------------------------------------------------------------------
// k_proj (per t): x_in = x[t] + x_out;  3x3 conv 2->128 + BN + LIF(vp).
// UNCHANGED arithmetic (margin-proven).  Spikes channel-last u8.
// ---------------------------------------------------------------------------
__global__ __launch_bounds__(256)
void k_proj(const float* __restrict__ xt, const float* __restrict__ xout,
            const float* __restrict__ wp,
            const float* __restrict__ g, const float* __restrict__ bb,
            const float* __restrict__ mm, const float* __restrict__ vv,
            float* __restrict__ vp, unsigned char* __restrict__ s1t) {
    __shared__ float xin[2 * 10 * 36];
    const int tid = threadIdx.x;
    const int b   = blockIdx.z >> 2;
    const int ocq = blockIdx.z & 3;
    const int gy0 = blockIdx.y * 8, gx0 = blockIdx.x * 32;

    for (int i = tid; i < 680; i += 256) {
        int ch = i / 340, rem = i % 340;
        int r = rem / 34, c = rem % 34;
        int gy = gy0 - 1 + r, gx = gx0 - 1 + c;
        float val = 0.f;
        if (gy >= 0 && gy < 128 && gx >= 0 && gx < 128) {
            int idx = ((b * 2 + ch) << 14) + (gy << 7) + gx;
            val = xt[idx] + xout[idx];
        }
        xin[(ch * 10 + r) * 36 + c] = val;
    }
    __syncthreads();

    const int prow = tid >> 5, pcol = tid & 31;
    float xw[2][3][3];
#pragma unroll
    for (int ch = 0; ch < 2; ++ch)
#pragma unroll
        for (int ky = 0; ky < 3; ++ky)
#pragma unroll
            for (int kx = 0; kx < 3; ++kx)
                xw[ch][ky][kx] = xin[(ch * 10 + prow + ky) * 36 + pcol + kx];

    const int pix = ((gy0 + prow) << 7) + gx0 + pcol;
    const int oc_beg = ocq * 32;
    unsigned int pk[8];
#pragma unroll
    for (int k = 0; k < 8; ++k) pk[k] = 0u;
#pragma unroll
    for (int oo = 0; oo < 32; ++oo) {
        const int oc = oc_beg + oo;
        float acc = 0.f;
#pragma unroll
        for (int ch = 0; ch < 2; ++ch)
#pragma unroll
            for (int ky = 0; ky < 3; ++ky)
#pragma unroll
                for (int kx = 0; kx < 3; ++kx)
                    acc = fmaf(wp[((oc * 2 + ch) * 3 + ky) * 3 + kx], xw[ch][ky][kx], acc);
        float sc = g[oc] / sqrtf(vv[oc] + 1e-5f);
        float h  = (acc - mm[oc]) * sc + bb[oc];
        int idx = ((b * 128 + oc) << 14) + pix;
        float v = vp[idx];
        v = v + (h - v) * 0.5f;
        bool s = (v >= 1.0f);
        vp[idx] = s ? 0.f : v;
        pk[oo >> 2] |= (s ? 1u : 0u) << ((oo & 3) * 8);
    }
    unsigned char* dst = s1t + ((((size_t)b << 14) + pix) << 7) + oc_beg;
    *(uint4*)dst        = make_uint4(pk[0], pk[1], pk[2], pk[3]);
    *(uint4*)(dst + 16) = make_uint4(pk[4], pk[5], pk[6], pk[7]);
}

// ---------------------------------------------------------------------------
// k_temp (per t): 3x3 conv 128->2 + BN + LIF(vtm); writes x_out spikes.
// UNCHANGED from round 5.
// ---------------------------------------------------------------------------
__global__ __launch_bounds__(128)
void k_temp(const unsigned char* __restrict__ s1t, const float* __restrict__ wt,
            const float* __restrict__ g, const float* __restrict__ bb,
            const float* __restrict__ mm, const float* __restrict__ vv,
            float* __restrict__ vtm, float* __restrict__ xout) {
    __shared__ unsigned char sl[49152];   // [icb 16][r 3][p 128] * 8B
    __shared__ float wls[2304];
    const int tid = threadIdx.x;
    const int b   = blockIdx.y;
    const int y0  = blockIdx.x;

    for (int i = tid; i < 2304; i += 128) wls[i] = wt[i];

    const unsigned char* sb = s1t + ((size_t)b << 21);
#pragma unroll
    for (int r = 0; r < 3; ++r) {
        int gy = y0 - 1 + r;
        bool ok = (gy >= 0 && gy < 128);
        const unsigned char* rowp = sb + ((size_t)gy << 14);
#pragma unroll
        for (int k = 0; k < 8; ++k) {
            int c = tid + k * 128;
            uint4 d = make_uint4(0u, 0u, 0u, 0u);
            if (ok) d = *(const uint4*)(rowp + c * 16);
            int p = c >> 3;
            int icb0 = (c & 7) * 2;
            int p0 = p ^ (icb0 & 7);
            int p1 = p ^ ((icb0 + 1) & 7);
            *(uint2*)&sl[(((icb0)     * 3 + r) * 128 + p0) * 8] = make_uint2(d.x, d.y);
            *(uint2*)&sl[(((icb0 + 1) * 3 + r) * 128 + p1) * 8] = make_uint2(d.z, d.w);
        }
    }
    __syncthreads();

    const int x = tid;
    float a0 = 0.f, a1 = 0.f;
#pragma unroll 1
    for (int icb = 0; icb < 16; ++icb) {
        int sw = icb & 7;
        const float* w0 = &wls[icb * 72];
        const float* w1 = &wls[1152 + icb * 72];
#pragma unroll
        for (int dy = 0; dy < 3; ++dy) {
#pragma unroll
            for (int dx = 0; dx < 3; ++dx) {
                int xx = x - 1 + dx;
                if (xx < 0 || xx > 127) continue;
                uint2 d = *(const uint2*)&sl[((icb * 3 + dy) * 128 + (xx ^ sw)) * 8];
                int tap = dy * 3 + dx;
#pragma unroll
                for (int j = 0; j < 4; ++j) {
                    float f0 = (float)((d.x >> (8 * j)) & 0xFFu);
                    float f1 = (float)((d.y >> (8 * j)) & 0xFFu);
                    a0 = fmaf(w0[j * 9 + tap],        f0, a0);
                    a0 = fmaf(w0[(4 + j) * 9 + tap],  f1, a0);
                    a1 = fmaf(w1[j * 9 + tap],        f0, a1);
                    a1 = fmaf(w1[(4 + j) * 9 + tap],  f1, a1);
                }
            }
        }
    }
#pragma unroll
    for (int oc = 0; oc < 2; ++oc) {
        float acc = (oc == 0) ? a0 : a1;
        float sc = g[oc] / sqrtf(vv[oc] + 1e-5f);
        float yv = (acc - mm[oc]) * sc + bb[oc];
        int idx = ((b * 2 + oc) << 14) + (y0 << 7) + x;
        float v = vtm[idx];
        v = v + (yv - v) * 0.5f;
        bool s = (v >= 1.0f);
        vtm[idx]  = s ? 0.f : v;
        xout[idx] = s ? 1.0f : 0.f;
    }
}

// ---------------------------------------------------------------------------
// k_fused (ROUND 6): operand roles SWAPPED — weights are the MFMA A-operand
// (m=lane&15 <-> oc; the weight-plane layout already matches), spikes are B
// (n=lane&15 <-> px; the LDS tile layout already matches).  D = [oc][px] is
// stored DIRECTLY from registers: no LDS transpose, no transpose bank
// conflicts, 2 barriers/t instead of 4.  px tile = 4 rows x 32 cols so every
// 128B out line is written whole by one wave back-to-back (kills the RMW
// write amplification seen in round 5: WRITE 1034MB for a 268MB output).
// BN folded into weights (w*sc, bias = acc init) to keep registers flat.
// LDS: 16 icb x 206-entry stride x 16B = 52.7KB; 3 blocks/CU (158KB<160KB).
// grid (4 oc-tiles, 512 px-tiles = b*128 + ry*4 + cx), block 256 = 4 waves.
// Wave tile: 32 oc (2 m-tiles) x 64 px (4 n-tiles); 24 MFMA per K32-step.
// ---------------------------------------------------------------------------
__global__ __launch_bounds__(256, 3)
void k_fused(const unsigned char* __restrict__ s1c,
             const short* __restrict__ whi, const short* __restrict__ wmid,
             const short* __restrict__ wlo,
             const short* __restrict__ rhi, const short* __restrict__ rmid,
             const short* __restrict__ rlo,
             const float* __restrict__ bias1, const float* __restrict__ biasr,
             float* __restrict__ out) {
    __shared__ __align__(16) char lds[52736];   // 16 icb * 206 entries * 16B

    const int tid = threadIdx.x;
    const int oc0 = blockIdx.x * 64;
    const int yb = blockIdx.y;
    const int b = yb >> 7, ry = (yb >> 2) & 31, cx = yb & 3;
    const int gy0 = ry * 4, gx0 = cx * 32;

    const int w   = tid >> 6, l = tid & 63;
    const int q   = l >> 4,  ln = l & 15;
    const int woc = w >> 1,  wpx = w & 1;

    // folded biases for this thread's 8 oc (mt x rg); acc init values
    f32x4 ba[2], brr[2];
#pragma unroll
    for (int mt = 0; mt < 2; ++mt)
#pragma unroll
        for (int rg = 0; rg < 4; ++rg) {
            int oc = oc0 + woc * 32 + mt * 16 + q * 4 + rg;
            ba[mt][rg]  = bias1[oc];
            brr[mt][rg] = biasr[oc];
        }

    // A (weights) lane offset: plane + ((kb*9+tap)*4+q)*2048 + (oc)*8
    const size_t wofs = ((size_t)q * 256 + oc0 + woc * 32 + ln) * 8;

    // B (spikes) per-nt tile coords and out store offsets
    int pb[4], po[4];
#pragma unroll
    for (int nt = 0; nt < 4; ++nt) {
        int px = wpx * 64 + nt * 16 + ln;
        int prow = px >> 5, pcol = px & 31;
        pb[nt] = prow * 34 + pcol;                       // entry index in tile
        po[nt] = ((gy0 + prow) << 7) + gx0 + pcol;       // out pixel offset
    }

    float va[4][2][4], vres[4][2][4];
#pragma unroll
    for (int nt = 0; nt < 4; ++nt)
#pragma unroll
        for (int mt = 0; mt < 2; ++mt)
#pragma unroll
            for (int rg = 0; rg < 4; ++rg) { va[nt][mt][rg] = 0.f; vres[nt][mt][rg] = 0.f; }

#pragma unroll 1
    for (int t = 0; t < 4; ++t) {
        const unsigned char* s1t = s1c + (size_t)t * 8388608 + ((size_t)b << 21);

        // ---- stage spike window: [icb 16][6 rows x 34 cols] 8-ic bf16 ----
        for (int cc = tid; cc < 3264; cc += 256) {
            int p = cc >> 4, icb = cc & 15;
            int r = p / 34, c = p - r * 34;
            int gy = gy0 - 1 + r, gx = gx0 - 1 + c;
            uint2 d = make_uint2(0u, 0u);
            if (gy >= 0 && gy < 128 && gx >= 0 && gx < 128)
                d = *(const uint2*)(s1t + ((size_t)((gy << 7) + gx) << 7) + icb * 8);
            uint4 pk;
            pk.x = ((d.x & 1u)          | ((d.x & 0x100u) << 8))   * 0x3F80u;
            pk.y = (((d.x >> 16) & 1u)  | ((d.x >> 8) & 0x10000u)) * 0x3F80u;
            pk.z = ((d.y & 1u)          | ((d.y & 0x100u) << 8))   * 0x3F80u;
            pk.w = (((d.y >> 16) & 1u)  | ((d.y >> 8) & 0x10000u)) * 0x3F80u;
            *(uint4*)(lds + (icb * 206 + p) * 16) = pk;
        }
        __syncthreads();

        f32x4 acc[4][2], accr[4][2];
#pragma unroll
        for (int nt = 0; nt < 4; ++nt)
#pragma unroll
            for (int mt = 0; mt < 2; ++mt) { acc[nt][mt] = ba[mt]; accr[nt][mt] = brr[mt]; }

        const short* bh = whi  + wofs;
        const short* bm = wmid + wofs;
        const short* bl = wlo  + wofs;

#pragma unroll 1
        for (int kb = 0; kb < 4; ++kb) {
            const char* bkb = lds + (size_t)(kb * 4 + q) * 3296;   // 206*16
#pragma unroll
            for (int ky = 0; ky < 3; ++ky) {
#pragma unroll
                for (int kx = 0; kx < 3; ++kx) {
                    short8 B4[4];
#pragma unroll
                    for (int nt = 0; nt < 4; ++nt)
                        B4[nt] = *(const short8*)(bkb + (pb[nt] + ky * 34 + kx) * 16);
                    short8 AH[2], AM[2], AL[2];
#pragma unroll
                    for (int mt = 0; mt < 2; ++mt) {
                        AH[mt] = *(const short8*)(bh + mt * 128);
                        AM[mt] = *(const short8*)(bm + mt * 128);
                        AL[mt] = *(const short8*)(bl + mt * 128);
                    }
#pragma unroll
                    for (int nt = 0; nt < 4; ++nt)
#pragma unroll
                        for (int mt = 0; mt < 2; ++mt) {
                            acc[nt][mt] = __builtin_amdgcn_mfma_f32_16x16x32_bf16(AH[mt], B4[nt], acc[nt][mt], 0, 0, 0);
                            acc[nt][mt] = __builtin_amdgcn_mfma_f32_16x16x32_bf16(AM[mt], B4[nt], acc[nt][mt], 0, 0, 0);
                            acc[nt][mt] = __builtin_amdgcn_mfma_f32_16x16x32_bf16(AL[mt], B4[nt], acc[nt][mt], 0, 0, 0);
                        }
                    if (ky == 1 && kx == 1) {   // 1x1 res conv on the center tap
                        short8 RH[2], RM[2], RL[2];
#pragma unroll
                        for (int mt = 0; mt < 2; ++mt) {
                            RH[mt] = *(const short8*)(rhi  + wofs + (size_t)kb * 8192 + mt * 128);
                            RM[mt] = *(const short8*)(rmid + wofs + (size_t)kb * 8192 + mt * 128);
                            RL[mt] = *(const short8*)(rlo  + wofs + (size_t)kb * 8192 + mt * 128);
                        }
#pragma unroll
                        for (int nt = 0; nt < 4; ++nt)
#pragma unroll
                            for (int mt = 0; mt < 2; ++mt) {
                                accr[nt][mt] = __builtin_amdgcn_mfma_f32_16x16x32_bf16(RH[mt], B4[nt], accr[nt][mt], 0, 0, 0);
                                accr[nt][mt] = __builtin_amdgcn_mfma_f32_16x16x32_bf16(RM[mt], B4[nt], accr[nt][mt], 0, 0, 0);
                                accr[nt][mt] = __builtin_amdgcn_mfma_f32_16x16x32_bf16(RL[mt], B4[nt], accr[nt][mt], 0, 0, 0);
                            }
                    }
                    bh += 8192; bm += 8192; bl += 8192;
                }
            }
        }
        __syncthreads();   // all LDS reads done; next t may restage

        // ---- LIF (both paths, BN already folded) + DIRECT stores ----
        const size_t tb = ((size_t)((t * 4 + b) * 256 + oc0)) << 14;
#pragma unroll
        for (int mt = 0; mt < 2; ++mt)
#pragma unroll
            for (int rg = 0; rg < 4; ++rg) {
                const size_t ob = tb + ((size_t)(woc * 32 + mt * 16 + q * 4 + rg) << 14);
#pragma unroll
                for (int nt = 0; nt < 4; ++nt) {
                    float ha = acc[nt][mt][rg];
                    float v = va[nt][mt][rg];
                    v = v + (ha - v) * 0.5f;
                    bool s = (v >= 1.0f);
                    va[nt][mt][rg] = s ? 0.f : v;
                    float sa = s ? 1.f : 0.f;

                    float hr = accr[nt][mt][rg];
                    float u = vres[nt][mt][rg];
                    u = u + (hr - u) * 0.5f;
                    bool sr_ = (u >= 1.0f);
                    vres[nt][mt][rg] = sr_ ? 0.f : u;

                    out[ob + po[nt]] = sa + (sr_ ? 1.f : 0.f);
                }
            }
    }
}

// ---------------------------------------------------------------------------
// Workspace layout (bytes):
//   s1c    @ 0          33,554,432  (u8 spikes CHANNEL-LAST [T][B][pix][128ic])
//   vp     @ 33,554,432 33,554,432  (float LIF state; DEAD after t-loop ->
//     weight planes overlap it:  whi @33,554,432 (589,824), wmid, wlo,
//     rhi @35,323,904 (65,536), rmid, rlo, bias1 @35,520,512 (1,024),
//     biasr @35,521,536 (1,024) — end 35,522,560)
//   vtm    @ 67,108,864    524,288
//   xout   @ 67,633,152    524,288     total = 68,157,440
// ---------------------------------------------------------------------------
extern "C" void kernel_launch(void* const* d_in, const int* in_sizes, int n_in,
                              void* d_out, int out_size, void* d_ws, size_t ws_size,
                              hipStream_t stream) {
    const float* x      = (const float*)d_in[0];
    const float* w_proj = (const float*)d_in[1];
    const float* g0 = (const float*)d_in[2];
    const float* b0 = (const float*)d_in[3];
    const float* m0 = (const float*)d_in[4];
    const float* v0 = (const float*)d_in[5];
    const float* w_temp = (const float*)d_in[6];
    const float* gt = (const float*)d_in[7];
    const float* bt = (const float*)d_in[8];
    const float* mt = (const float*)d_in[9];
    const float* vt = (const float*)d_in[10];
    const float* w1 = (const float*)d_in[11];
    const float* g1 = (const float*)d_in[12];
    const float* b1 = (const float*)d_in[13];
    const float* m1 = (const float*)d_in[14];
    const float* v1 = (const float*)d_in[15];
    const float* w_res = (const float*)d_in[16];
    const float* gr = (const float*)d_in[17];
    const float* br = (const float*)d_in[18];
    const float* mr = (const float*)d_in[19];
    const float* vr = (const float*)d_in[20];

    char* ws = (char*)d_ws;
    unsigned char* s1c = (unsigned char*)ws;
    float* vp    = (float*)(ws + 33554432);
    short* whi   = (short*)(ws + 33554432);   // overlaps vp (dead after t-loop)
    short* wmid  = (short*)(ws + 34144256);
    short* wlo   = (short*)(ws + 34734080);
    short* rhi   = (short*)(ws + 35323904);
    short* rmid  = (short*)(ws + 35389440);
    short* rlo   = (short*)(ws + 35454976);
    float* bias1 = (float*)(ws + 35520512);
    float* biasr = (float*)(ws + 35521536);
    float* vtm   = (float*)(ws + 67108864);
    float* xout  = (float*)(ws + 67633152);

    // zero LIF states + recurrent x_out
    hipMemsetAsync(ws + 33554432, 0, 34603008, stream);

    for (int t = 0; t < 4; ++t) {
        const float* xt = x + (size_t)t * 4 * 2 * HW;
        unsigned char* s1t = s1c + (size_t)t * 8388608;
        k_proj<<<dim3(4, 16, 16), dim3(256), 0, stream>>>(
            xt, xout, w_proj, g0, b0, m0, v0, vp, s1t);
        k_temp<<<dim3(128, 4), dim3(128), 0, stream>>>(
            s1t, w_temp, gt, bt, mt, vt, vtm, xout);
    }

    // weights reorder AFTER the t-loop (vp is dead, planes overlap it)
    k_reorder3<<<dim3(1152), dim3(256), 0, stream>>>(
        w1, w_res, g1, b1, m1, v1, gr, br, mr, vr,
        whi, wmid, wlo, rhi, rmid, rlo, bias1, biasr);

    k_fused<<<dim3(4, 512), dim3(256), 0, stream>>>(
        s1c, whi, wmid, wlo, rhi, rmid, rlo, bias1, biasr, (float*)d_out);
}

// Round 7
// 952.388 us; speedup vs baseline: 5.5504x; 1.1899x over previous
//
#include <hip/hip_runtime.h>
#include <math.h>

// Problem constants: T=4, B=4, C=2, H=W=128 (HW=16384), E=256, half=128.
#define HW 16384

typedef __attribute__((ext_vector_type(8))) _Float16 half8;
typedef __attribute__((ext_vector_type(4))) float f32x4;

// ---------------------------------------------------------------------------
// k_reorder2: BN-folded 2-plane fp16 split of (w*sc)*4096 into MFMA-A layout:
// plane[kb 4][tap 9][quad 4][oc 256][j 8], ic = kb*32+q*8+j.
// fp16 has 11 significant bits -> hi+mid covers 22 of fp32's 24; residual
// <= 2^-22|w| random-sign (rms ~2e-7 in h — 10x below the accumulation-order
// noise already proven safe by five absmax-0.0 rounds).  The 2^12 scale
// (exact, undone in the epilogue) keeps all plane values in fp16-normal
// range.  Biases emitted pre-scaled by 4096 (acc init).
// ---------------------------------------------------------------------------
__global__ __launch_bounds__(256)
void k_reorder2(const float* __restrict__ w1, const float* __restrict__ wres,
                const float* __restrict__ g1, const float* __restrict__ b1,
                const float* __restrict__ m1, const float* __restrict__ v1,
                const float* __restrict__ gr, const float* __restrict__ br,
                const float* __restrict__ mr, const float* __restrict__ vr,
                short* __restrict__ whi, short* __restrict__ wmid,
                short* __restrict__ rhi, short* __restrict__ rmid,
                float* __restrict__ bias1, float* __restrict__ biasr) {
    int i = blockIdx.x * 256 + threadIdx.x;
    if (i < 294912) {                 // 256 oc * 128 ic * 9 taps
        int n = i / 1152, rem = i % 1152;
        int ic = rem / 9, tap = rem % 9;
        float sc = g1[n] / sqrtf(v1[n] + 1e-5f);
        float wv = (w1[i] * sc) * 4096.0f;
        _Float16 h = (_Float16)wv;            // RNE
        float r1 = wv - (float)h;
        _Float16 m = (_Float16)r1;
        int kb = ic >> 5, q = (ic >> 3) & 3, j = ic & 7;
        size_t f = ((((size_t)(kb * 9 + tap)) * 4 + q) * 256 + n) * 8 + j;
        whi[f]  = __builtin_bit_cast(short, h);
        wmid[f] = __builtin_bit_cast(short, m);
    }
    if (i < 32768) {                  // 256 oc * 128 ic
        int n = i >> 7, ic = i & 127;
        float sc = gr[n] / sqrtf(vr[n] + 1e-5f);
        float wv = (wres[i] * sc) * 4096.0f;
        _Float16 h = (_Float16)wv;
        float r1 = wv - (float)h;
        _Float16 m = (_Float16)r1;
        int kb = ic >> 5, q = (ic >> 3) & 3, j = ic & 7;
        size_t f = (((size_t)kb * 4 + q) * 256 + n) * 8 + j;
        rhi[f]  = __builtin_bit_cast(short, h);
        rmid[f] = __builtin_bit_cast(short, m);
    }
    if (i < 256) {
        float sc1 = g1[i] / sqrtf(v1[i] + 1e-5f);
        bias1[i] = (b1[i] - m1[i] * sc1) * 4096.0f;
        float scr_ = gr[i] / sqrtf(vr[i] + 1e-5f);
        biasr[i] = (br[i] - mr[i] * scr_) * 4096.0f;
    }
}

// ---------------------------------------------------------------------------
// k_proj (per t): x_in = x[t] + (first ? 0 : x_out);  3x3 conv 2->128 + BN +
// LIF(vp, state skipped-read at t=0 -> no memset needed).
// Spikes CHANNEL-LAST u8.  grid (4,16,16), block 256.
// ---------------------------------------------------------------------------
__global__ __launch_bounds__(256)
void k_proj(const float* __restrict__ xt, const float* __restrict__ xout,
            const float* __restrict__ wp,
            const float* __restrict__ g, const float* __restrict__ bb,
            const float* __restrict__ mm, const float* __restrict__ vv,
            float* __restrict__ vp, unsigned char* __restrict__ s1t, int first) {
    __shared__ float xin[2 * 10 * 36];
    const int tid = threadIdx.x;
    const int b   = blockIdx.z >> 2;
    const int ocq = blockIdx.z & 3;
    const int gy0 = blockIdx.y * 8, gx0 = blockIdx.x * 32;

    for (int i = tid; i < 680; i += 256) {
        int ch = i / 340, rem = i % 340;
        int r = rem / 34, c = rem % 34;
        int gy = gy0 - 1 + r, gx = gx0 - 1 + c;
        float val = 0.f;
        if (gy >= 0 && gy < 128 && gx >= 0 && gx < 128) {
            int idx = ((b * 2 + ch) << 14) + (gy << 7) + gx;
            val = xt[idx];
            if (!first) val += xout[idx];
        }
        xin[(ch * 10 + r) * 36 + c] = val;
    }
    __syncthreads();

    const int prow = tid >> 5, pcol = tid & 31;
    float xw[2][3][3];
#pragma unroll
    for (int ch = 0; ch < 2; ++ch)
#pragma unroll
        for (int ky = 0; ky < 3; ++ky)
#pragma unroll
            for (int kx = 0; kx < 3; ++kx)
                xw[ch][ky][kx] = xin[(ch * 10 + prow + ky) * 36 + pcol + kx];

    const int pix = ((gy0 + prow) << 7) + gx0 + pcol;
    const int oc_beg = ocq * 32;
    unsigned int pk[8];
#pragma unroll
    for (int k = 0; k < 8; ++k) pk[k] = 0u;
#pragma unroll
    for (int oo = 0; oo < 32; ++oo) {
        const int oc = oc_beg + oo;
        float acc = 0.f;
#pragma unroll
        for (int ch = 0; ch < 2; ++ch)
#pragma unroll
            for (int ky = 0; ky < 3; ++ky)
#pragma unroll
                for (int kx = 0; kx < 3; ++kx)
                    acc = fmaf(wp[((oc * 2 + ch) * 3 + ky) * 3 + kx], xw[ch][ky][kx], acc);
        float sc = g[oc] / sqrtf(vv[oc] + 1e-5f);
        float h  = (acc - mm[oc]) * sc + bb[oc];
        int idx = ((b * 128 + oc) << 14) + pix;
        float v = first ? 0.f : vp[idx];
        v = v + (h - v) * 0.5f;
        bool s = (v >= 1.0f);
        vp[idx] = s ? 0.f : v;
        pk[oo >> 2] |= (s ? 1u : 0u) << ((oo & 3) * 8);
    }
    unsigned char* dst = s1t + ((((size_t)b << 14) + pix) << 7) + oc_beg;
    *(uint4*)dst        = make_uint4(pk[0], pk[1], pk[2], pk[3]);
    *(uint4*)(dst + 16) = make_uint4(pk[4], pk[5], pk[6], pk[7]);
}

// ---------------------------------------------------------------------------
// k_temp (per t): 3x3 conv 128->2 + BN + LIF(vtm, skip-read at t=0);
// writes x_out spikes (float).  grid (128,4), block 128.
// ---------------------------------------------------------------------------
__global__ __launch_bounds__(128)
void k_temp(const unsigned char* __restrict__ s1t, const float* __restrict__ wt,
            const float* __restrict__ g, const float* __restrict__ bb,
            const float* __restrict__ mm, const float* __restrict__ vv,
            float* __restrict__ vtm, float* __restrict__ xout, int first) {
    __shared__ unsigned char sl[49152];   // [icb 16][r 3][p 128] * 8B
    __shared__ float wls[2304];
    const int tid = threadIdx.x;
    const int b   = blockIdx.y;
    const int y0  = blockIdx.x;

    for (int i = tid; i < 2304; i += 128) wls[i] = wt[i];

    const unsigned char* sb = s1t + ((size_t)b << 21);
#pragma unroll
    for (int r = 0; r < 3; ++r) {
        int gy = y0 - 1 + r;
        bool ok = (gy >= 0 && gy < 128);
        const unsigned char* rowp = sb + ((size_t)gy << 14);
#pragma unroll
        for (int k = 0; k < 8; ++k) {
            int c = tid + k * 128;
            uint4 d = make_uint4(0u, 0u, 0u, 0u);
            if (ok) d = *(const uint4*)(rowp + c * 16);
            int p = c >> 3;
            int icb0 = (c & 7) * 2;
            int p0 = p ^ (icb0 & 7);
            int p1 = p ^ ((icb0 + 1) & 7);
            *(uint2*)&sl[(((icb0)     * 3 + r) * 128 + p0) * 8] = make_uint2(d.x, d.y);
            *(uint2*)&sl[(((icb0 + 1) * 3 + r) * 128 + p1) * 8] = make_uint2(d.z, d.w);
        }
    }
    __syncthreads();

    const int x = tid;
    float a0 = 0.f, a1 = 0.f;
#pragma unroll 1
    for (int icb = 0; icb < 16; ++icb) {
        int sw = icb & 7;
        const float* w0 = &wls[icb * 72];
        const float* w1 = &wls[1152 + icb * 72];
#pragma unroll
        for (int dy = 0; dy < 3; ++dy) {
#pragma unroll
            for (int dx = 0; dx < 3; ++dx) {
                int xx = x - 1 + dx;
                if (xx < 0 || xx > 127) continue;
                uint2 d = *(const uint2*)&sl[((icb * 3 + dy) * 128 + (xx ^ sw)) * 8];
                int tap = dy * 3 + dx;
#pragma unroll
                for (int j = 0; j < 4; ++j) {
                    float f0 = (float)((d.x >> (8 * j)) & 0xFFu);
                    float f1 = (float)((d.y >> (8 * j)) & 0xFFu);
                    a0 = fmaf(w0[j * 9 + tap],        f0, a0);
                    a0 = fmaf(w0[(4 + j) * 9 + tap],  f1, a0);
                    a1 = fmaf(w1[j * 9 + tap],        f0, a1);
                    a1 = fmaf(w1[(4 + j) * 9 + tap],  f1, a1);
                }
            }
        }
    }
#pragma unroll
    for (int oc = 0; oc < 2; ++oc) {
        float acc = (oc == 0) ? a0 : a1;
        float sc = g[oc] / sqrtf(vv[oc] + 1e-5f);
        float yv = (acc - mm[oc]) * sc + bb[oc];
        int idx = ((b * 2 + oc) << 14) + (y0 << 7) + x;
        float v = first ? 0.f : vtm[idx];
        v = v + (yv - v) * 0.5f;
        bool s = (v >= 1.0f);
        vtm[idx]  = s ? 0.f : v;
        xout[idx] = s ? 1.0f : 0.f;
    }
}

// ---------------------------------------------------------------------------
// k_fused (ROUND 7): round-6 structure (weights=A, spikes=B, direct stores,
// 2 barriers/t) with the 3-plane bf16 split replaced by a 2-plane fp16 split
// (fp16: 11 significant bits; hi+mid = 22 of fp32's 24; residual 2^-22|w|
// random-sign — rms ~2e-7 in h, 10x below the accumulation-order noise five
// prior rounds survived at absmax 0.0).  Planes carry a 2^12 scale (exact),
// undone in the epilogue: h = acc * 2^-12; acc init = 4096*bias.
// MFMA per K-step: 30 -> 20.  A-operand L2 traffic: 7.2 -> 4.8 GB.
// grid (4 oc-tiles, 512 px-tiles = b*128 + ry*4 + cx), block 256 = 4 waves.
// ---------------------------------------------------------------------------
__global__ __launch_bounds__(256, 3)
void k_fused(const unsigned char* __restrict__ s1c,
             const short* __restrict__ whi, const short* __restrict__ wmid,
             const short* __restrict__ rhi, const short* __restrict__ rmid,
             const float* __restrict__ bias1, const float* __restrict__ biasr,
             float* __restrict__ out) {
    __shared__ __align__(16) char lds[52736];   // 16 icb * 206 entries * 16B

    const int tid = threadIdx.x;
    const int oc0 = blockIdx.x * 64;
    const int yb = blockIdx.y;
    const int b = yb >> 7, ry = (yb >> 2) & 31, cx = yb & 3;
    const int gy0 = ry * 4, gx0 = cx * 32;

    const int w   = tid >> 6, l = tid & 63;
    const int q   = l >> 4,  ln = l & 15;
    const int woc = w >> 1,  wpx = w & 1;

    // pre-scaled folded biases (acc init)
    f32x4 ba[2], brr[2];
#pragma unroll
    for (int mt = 0; mt < 2; ++mt)
#pragma unroll
        for (int rg = 0; rg < 4; ++rg) {
            int oc = oc0 + woc * 32 + mt * 16 + q * 4 + rg;
            ba[mt][rg]  = bias1[oc];
            brr[mt][rg] = biasr[oc];
        }

    const size_t wofs = ((size_t)q * 256 + oc0 + woc * 32 + ln) * 8;

    int pb[4], po[4];
#pragma unroll
    for (int nt = 0; nt < 4; ++nt) {
        int px = wpx * 64 + nt * 16 + ln;
        int prow = px >> 5, pcol = px & 31;
        pb[nt] = prow * 34 + pcol;
        po[nt] = ((gy0 + prow) << 7) + gx0 + pcol;
    }

    float va[4][2][4], vres[4][2][4];
#pragma unroll
    for (int nt = 0; nt < 4; ++nt)
#pragma unroll
        for (int mt = 0; mt < 2; ++mt)
#pragma unroll
            for (int rg = 0; rg < 4; ++rg) { va[nt][mt][rg] = 0.f; vres[nt][mt][rg] = 0.f; }

#pragma unroll 1
    for (int t = 0; t < 4; ++t) {
        const unsigned char* s1t = s1c + (size_t)t * 8388608 + ((size_t)b << 21);

        // ---- stage spike window: [icb 16][6 rows x 34 cols] 8-ic fp16 ----
        for (int cc = tid; cc < 3264; cc += 256) {
            int p = cc >> 4, icb = cc & 15;
            int r = p / 34, c = p - r * 34;
            int gy = gy0 - 1 + r, gx = gx0 - 1 + c;
            uint2 d = make_uint2(0u, 0u);
            if (gy >= 0 && gy < 128 && gx >= 0 && gx < 128)
                d = *(const uint2*)(s1t + ((size_t)((gy << 7) + gx) << 7) + icb * 8);
            uint4 pk;                      // fp16 1.0 = 0x3C00
            pk.x = ((d.x & 1u)          | ((d.x & 0x100u) << 8))   * 0x3C00u;
            pk.y = (((d.x >> 16) & 1u)  | ((d.x >> 8) & 0x10000u)) * 0x3C00u;
            pk.z = ((d.y & 1u)          | ((d.y & 0x100u) << 8))   * 0x3C00u;
            pk.w = (((d.y >> 16) & 1u)  | ((d.y >> 8) & 0x10000u)) * 0x3C00u;
            *(uint4*)(lds + (icb * 206 + p) * 16) = pk;
        }
        __syncthreads();

        f32x4 acc[4][2], accr[4][2];
#pragma unroll
        for (int nt = 0; nt < 4; ++nt)
#pragma unroll
            for (int mt = 0; mt < 2; ++mt) { acc[nt][mt] = ba[mt]; accr[nt][mt] = brr[mt]; }

        const short* bh = whi  + wofs;
        const short* bm = wmid + wofs;

#pragma unroll 1
        for (int kb = 0; kb < 4; ++kb) {
            const char* bkb = lds + (size_t)(kb * 4 + q) * 3296;   // 206*16
#pragma unroll
            for (int ky = 0; ky < 3; ++ky) {
#pragma unroll
                for (int kx = 0; kx < 3; ++kx) {
                    half8 B4[4];
#pragma unroll
                    for (int nt = 0; nt < 4; ++nt)
                        B4[nt] = *(const half8*)(bkb + (pb[nt] + ky * 34 + kx) * 16);
                    half8 AH[2], AM[2];
#pragma unroll
                    for (int mt = 0; mt < 2; ++mt) {
                        AH[mt] = *(const half8*)(bh + mt * 128);
                        AM[mt] = *(const half8*)(bm + mt * 128);
                    }
#pragma unroll
                    for (int nt = 0; nt < 4; ++nt)
#pragma unroll
                        for (int mt = 0; mt < 2; ++mt) {
                            acc[nt][mt] = __builtin_amdgcn_mfma_f32_16x16x32_f16(AH[mt], B4[nt], acc[nt][mt], 0, 0, 0);
                            acc[nt][mt] = __builtin_amdgcn_mfma_f32_16x16x32_f16(AM[mt], B4[nt], acc[nt][mt], 0, 0, 0);
                        }
                    if (ky == 1 && kx == 1) {   // 1x1 res conv on the center tap
                        half8 RH[2], RM[2];
#pragma unroll
                        for (int mt = 0; mt < 2; ++mt) {
                            RH[mt] = *(const half8*)(rhi  + wofs + (size_t)kb * 8192 + mt * 128);
                            RM[mt] = *(const half8*)(rmid + wofs + (size_t)kb * 8192 + mt * 128);
                        }
#pragma unroll
                        for (int nt = 0; nt < 4; ++nt)
#pragma unroll
                            for (int mt = 0; mt < 2; ++mt) {
                                accr[nt][mt] = __builtin_amdgcn_mfma_f32_16x16x32_f16(RH[mt], B4[nt], accr[nt][mt], 0, 0, 0);
                                accr[nt][mt] = __builtin_amdgcn_mfma_f32_16x16x32_f16(RM[mt], B4[nt], accr[nt][mt], 0, 0, 0);
                            }
                    }
                    bh += 8192; bm += 8192;
                }
            }
        }
        __syncthreads();   // all LDS reads done; next t may restage

        // ---- LIF (both paths; undo the 2^12 plane scale) + direct stores ----
        const float ds_ = 0.000244140625f;   // 2^-12, exact
        const size_t tb = ((size_t)((t * 4 + b) * 256 + oc0)) << 14;
#pragma unroll
        for (int mt = 0; mt < 2; ++mt)
#pragma unroll
            for (int rg = 0; rg < 4; ++rg) {
                const size_t ob = tb + ((size_t)(woc * 32 + mt * 16 + q * 4 + rg) << 14);
#pragma unroll
                for (int nt = 0; nt < 4; ++nt) {
                    float ha = acc[nt][mt][rg] * ds_;
                    float v = va[nt][mt][rg];
                    v = v + (ha - v) * 0.5f;
                    bool s = (v >= 1.0f);
                    va[nt][mt][rg] = s ? 0.f : v;
                    float sa = s ? 1.f : 0.f;

                    float hr = accr[nt][mt][rg] * ds_;
                    float u = vres[nt][mt][rg];
                    u = u + (hr - u) * 0.5f;
                    bool sr_ = (u >= 1.0f);
                    vres[nt][mt][rg] = sr_ ? 0.f : u;

                    out[ob + po[nt]] = sa + (sr_ ? 1.f : 0.f);
                }
            }
    }
}

// ---------------------------------------------------------------------------
// Workspace layout (bytes):
//   s1c    @ 0          33,554,432  (u8 spikes CHANNEL-LAST [T][B][pix][128ic])
//   vp     @ 33,554,432 33,554,432  (LIF state; t=0 skip-read -> NO memset;
//     dead after t-loop -> fp16 weight planes overlap it:
//     whi @33,554,432 (589,824), wmid @34,144,256 (589,824),
//     rhi @34,734,080 (65,536), rmid @34,799,616 (65,536),
//     bias1 @34,865,152 (1,024), biasr @34,866,176 (1,024))
//   vtm    @ 67,108,864    524,288  (t=0 skip-read)
//   xout   @ 67,633,152    524,288  (t=0 not read)   total = 68,157,440
// ---------------------------------------------------------------------------
extern "C" void kernel_launch(void* const* d_in, const int* in_sizes, int n_in,
                              void* d_out, int out_size, void* d_ws, size_t ws_size,
                              hipStream_t stream) {
    const float* x      = (const float*)d_in[0];
    const float* w_proj = (const float*)d_in[1];
    const float* g0 = (const float*)d_in[2];
    const float* b0 = (const float*)d_in[3];
    const float* m0 = (const float*)d_in[4];
    const float* v0 = (const float*)d_in[5];
    const float* w_temp = (const float*)d_in[6];
    const float* gt = (const float*)d_in[7];
    const float* bt = (const float*)d_in[8];
    const float* mt = (const float*)d_in[9];
    const float* vt = (const float*)d_in[10];
    const float* w1 = (const float*)d_in[11];
    const float* g1 = (const float*)d_in[12];
    const float* b1 = (const float*)d_in[13];
    const float* m1 = (const float*)d_in[14];
    const float* v1 = (const float*)d_in[15];
    const float* w_res = (const float*)d_in[16];
    const float* gr = (const float*)d_in[17];
    const float* br = (const float*)d_in[18];
    const float* mr = (const float*)d_in[19];
    const float* vr = (const float*)d_in[20];

    char* ws = (char*)d_ws;
    unsigned char* s1c = (unsigned char*)ws;
    float* vp    = (float*)(ws + 33554432);
    short* whi   = (short*)(ws + 33554432);   // overlaps vp (dead after t-loop)
    short* wmid  = (short*)(ws + 34144256);
    short* rhi   = (short*)(ws + 34734080);
    short* rmid  = (short*)(ws + 34799616);
    float* bias1 = (float*)(ws + 34865152);
    float* biasr = (float*)(ws + 34866176);
    float* vtm   = (float*)(ws + 67108864);
    float* xout  = (float*)(ws + 67633152);

    for (int t = 0; t < 4; ++t) {
        const float* xt = x + (size_t)t * 4 * 2 * HW;
        unsigned char* s1t = s1c + (size_t)t * 8388608;
        k_proj<<<dim3(4, 16, 16), dim3(256), 0, stream>>>(
            xt, xout, w_proj, g0, b0, m0, v0, vp, s1t, t == 0);
        k_temp<<<dim3(128, 4), dim3(128), 0, stream>>>(
            s1t, w_temp, gt, bt, mt, vt, vtm, xout, t == 0);
    }

    // weights reorder AFTER the t-loop (vp is dead, planes overlap it)
    k_reorder2<<<dim3(1152), dim3(256), 0, stream>>>(
        w1, w_res, g1, b1, m1, v1, gr, br, mr, vr,
        whi, wmid, rhi, rmid, bias1, biasr);

    k_fused<<<dim3(4, 512), dim3(256), 0, stream>>>(
        s1c, whi, wmid, rhi, rmid, bias1, biasr, (float*)d_out);
}